// Round 11
// baseline (451.831 us; speedup 1.0000x reference)
//
#include <hip/hip_runtime.h>
#include <math.h>

#define DIM 384
#define NUM_HEADS 8
#define RES 14
#define RES2 7
#define NPOS 196
#define N2 49
#define DHEAD 64
#define NH_KD 128
#define DH 512
#define OUT_DIM 768
#define BATCH 512
#define SCALE_Q 0.25f

typedef unsigned short u16;
typedef short s16x8 __attribute__((ext_vector_type(8)));
typedef short s16x4 __attribute__((ext_vector_type(4)));
typedef float f32x4 __attribute__((ext_vector_type(4)));
typedef unsigned int u32x2 __attribute__((ext_vector_type(2)));

__device__ __forceinline__ float bf2f(u16 u) {
  union { unsigned int i; float f; } v; v.i = ((unsigned int)u) << 16; return v.f;
}
__device__ __forceinline__ u16 f2bf(float f) {
  union { unsigned int i; float f; } v; v.f = f;
  unsigned int r = v.i + 0x7fffu + ((v.i >> 16) & 1u);
  return (u16)(r >> 16);
}

#define GLD16(gp, lp) __builtin_amdgcn_global_load_lds( \
    (const __attribute__((address_space(1))) void*)(gp), \
    (__attribute__((address_space(3))) void*)(lp), 16, 0, 0)

// ---------- fused prep: weight casts + bias gather in one launch ----------
__global__ __launch_bounds__(256) void k_prep(const float* __restrict__ kw, const float* __restrict__ vw,
                                              const float* __restrict__ qw, const float* __restrict__ pw,
                                              const float* __restrict__ ab, const int* __restrict__ idxs, int noff,
                                              u16* __restrict__ kwb, u16* __restrict__ vwb,
                                              u16* __restrict__ qwb, u16* __restrict__ pwb,
                                              float* __restrict__ bxp) {
  int i = blockIdx.x * 256 + threadIdx.x;
  const int e1 = NH_KD * DIM;                // 49152
  const int e2 = e1 + DH * DIM;              // 245760
  const int e3 = e2 + NH_KD * DIM;           // 294912
  const int e4 = e3 + OUT_DIM * DH;          // 688128
  const int e5 = e4 + NUM_HEADS * N2 * 256;  // 788480
  if (i < e1) kwb[i] = f2bf(kw[i]);
  else if (i < e2) vwb[i - e1] = f2bf(vw[i - e1]);
  else if (i < e3) qwb[i - e2] = f2bf(qw[i - e2]);
  else if (i < e4) pwb[i - e3] = f2bf(pw[i - e3]);
  else if (i < e5) {
    int j = i - e4;
    int f = j & 15, c = (j >> 4) & 15;
    int m = (j >> 8) % N2, h = j / (N2 * 256);
    int n = f * 16 + c;
    bxp[j] = (n < NPOS) ? ab[h * noff + idxs[m * NPOS + n]] : 0.f;
  }
}

// ---------- fused: x transpose (f32 [b][384][196] -> bf16 xbT [b][196][384])
//            + depthwise dwconv_q for this block's 64-channel chunk -> qlT ----------
// Depthwise conv needs only its own channel: tile[64ch][196pos] already holds everything.
__global__ __launch_bounds__(256) void k_transpose_dwq(const float* __restrict__ x, u16* __restrict__ xt,
                                                       const float* __restrict__ qlw, const float* __restrict__ qlb,
                                                       u16* __restrict__ qlt) {
  int b = blockIdx.y, c0 = blockIdx.x * 64;
  __shared__ u16 tile[64][196];
  __shared__ float wlds[576];   // 64 ch x 9 taps
  __shared__ float blds[64];
  int tid = threadIdx.x, wave = tid >> 6, lane = tid & 63;
  const float* xb = x + (size_t)b * DIM * NPOS;
  for (int r = wave; r < 64; r += 4) {
    const float* row = xb + (size_t)(c0 + r) * NPOS;
    tile[r][lane]       = f2bf(row[lane]);
    tile[r][lane + 64]  = f2bf(row[lane + 64]);
    tile[r][lane + 128] = f2bf(row[lane + 128]);
    if (lane < 4) tile[r][lane + 192] = f2bf(row[lane + 192]);
  }
  for (int i = tid; i < 576; i += 256) wlds[i] = qlw[c0 * 9 + i];
  if (tid < 64) blds[tid] = qlb[c0 + tid];
  __syncthreads();
  u16* xtb = xt + (size_t)b * NPOS * DIM;
  for (int n = wave; n < NPOS; n += 4)
    xtb[(size_t)n * DIM + c0 + lane] = tile[lane][n];
  // dwconv_q: out[n2][c0+cl], n2 wave-uniform per iteration
  for (int idx = tid; idx < 64 * N2; idx += 256) {
    int cl = idx & 63, n2 = idx >> 6;
    int r = n2 / RES2, s = n2 % RES2;
    float acc = blds[cl] + bf2f(tile[cl][(2 * r) * RES + 2 * s]);  // bias + strided residual
#pragma unroll
    for (int dy = 0; dy < 3; dy++) {
      int ry = 2 * r - 1 + dy;
      if (ry < 0 || ry >= RES) continue;
#pragma unroll
      for (int dx = 0; dx < 3; dx++) {
        int sx = 2 * s - 1 + dx;
        if (sx < 0 || sx >= RES) continue;
        acc += wlds[cl * 9 + dy * 3 + dx] * bf2f(tile[cl][ry * RES + sx]);
      }
    }
    qlt[((size_t)b * N2 + n2) * DIM + c0 + cl] = f2bf(acc);
  }
}

// ---------- combined v/k/q GEMM, one launch, K=384 for all ----------
// 128x128 tile, BK=64 (two 8KB 32-K halves/operand, one barrier per 64-K), GLD16 staging.
// chunk = 1KB = 16 rows x 64B; wave w stages chunks w*2, w*2+1.
// Source pre-swizzle (m173/rule21): lane fetches global granule (l&3)^((l>>3)&3);
// frag reads un-swizzle with rg8 = ((l>>4)^((l>>1)&3))*8 -> conflict-free both sides.
// Segments: bx<3136 v (A=vwb m=ch, B=xbT n=j, mode1 store v4m[b][512][196]);
//           bx<3920 k (A=xbT m=j, B=kwb n=ch, mode0 kTm[j][128]);
//           else    q (A=qlT m=j, B=qwb n=ch, mode0 qTm[j][128]).
__global__ __launch_bounds__(256) void k_gemm3(
    const u16* __restrict__ xbT, const u16* __restrict__ qlT,
    const u16* __restrict__ vwb, const u16* __restrict__ kwb, const u16* __restrict__ qwb,
    u16* __restrict__ v4m, u16* __restrict__ kTm, u16* __restrict__ qTm,
    const float* __restrict__ vb, const float* __restrict__ vbs, const float* __restrict__ vbt,
    const float* __restrict__ kb, const float* __restrict__ kbs, const float* __restrict__ kbt,
    const float* __restrict__ qpb, const float* __restrict__ qbs, const float* __restrict__ qbt) {
  __shared__ __align__(16) u16 a_lds[2 * 128 * 32];
  __shared__ __align__(16) u16 b_lds[2 * 128 * 32];
  int bx = blockIdx.x;
  const u16 *A, *B; u16* C;
  const float *cb, *bns, *bnt;
  int NMT, ldc, mode, lnwg, lbx;
  if (bx < 3136)      { A = vwb; B = xbT; C = v4m; cb = vb;  bns = vbs; bnt = vbt; NMT = 4;   ldc = 0;     mode = 1; lnwg = 3136; lbx = bx; }
  else if (bx < 3920) { A = xbT; B = kwb; C = kTm; cb = kb;  bns = kbs; bnt = kbt; NMT = 784; ldc = NH_KD; mode = 0; lnwg = 784;  lbx = bx - 3136; }
  else                { A = qlT; B = qwb; C = qTm; cb = qpb; bns = qbs; bnt = qbt; NMT = 196; ldc = NH_KD; mode = 0; lnwg = 196;  lbx = bx - 3920; }
  int wg = ((lnwg & 7) == 0) ? ((lbx & 7) * (lnwg >> 3) + (lbx >> 3)) : lbx;  // XCD-bijective per segment
  int mt = wg % NMT, nt = wg / NMT;
  int m0 = mt * 128, n0 = nt * 128;
  int tid = threadIdx.x, w = tid >> 6, l = tid & 63;

  int srow = l >> 2;
  int scol = ((l & 3) ^ ((l >> 3) & 3)) * 8;   // pre-swizzled source granule
  const u16* asrc[2]; const u16* bsrc[2];
#pragma unroll
  for (int c = 0; c < 2; c++) {
    int chunk = w * 2 + c;
    asrc[c] = A + (size_t)(m0 + chunk * 16 + srow) * DIM + scol;
    bsrc[c] = B + (size_t)(n0 + chunk * 16 + srow) * DIM + scol;
  }
  char* adst = (char*)a_lds + (w * 2) * 1024 + l * 16;
  char* bdst = (char*)b_lds + (w * 2) * 1024 + l * 16;

  f32x4 acc[4][4];
#pragma unroll
  for (int i = 0; i < 4; i++)
#pragma unroll
    for (int j = 0; j < 4; j++) acc[i][j] = (f32x4){0.f, 0.f, 0.f, 0.f};

  int wm = w >> 1, wn = w & 1;
  int rg8 = ((l >> 4) ^ ((l >> 1) & 3)) * 8;   // un-swizzling read granule
  int arow = wm * 64 + (l & 15);
  int brow = wn * 64 + (l & 15);

  for (int kk = 0; kk < DIM; kk += 64) {
#pragma unroll
    for (int c = 0; c < 2; c++) {
      GLD16(asrc[c] + kk,      adst + c * 1024);
      GLD16(asrc[c] + kk + 32, adst + 8192 + c * 1024);
      GLD16(bsrc[c] + kk,      bdst + c * 1024);
      GLD16(bsrc[c] + kk + 32, bdst + 8192 + c * 1024);
    }
    __syncthreads();
#pragma unroll
    for (int hf = 0; hf < 2; hf++) {
      const u16* ah = a_lds + hf * (128 * 32);
      const u16* bh = b_lds + hf * (128 * 32);
      s16x8 af[4], bf[4];
#pragma unroll
      for (int i = 0; i < 4; i++) {
        af[i] = *(const s16x8*)(&ah[(arow + i * 16) * 32 + rg8]);
        bf[i] = *(const s16x8*)(&bh[(brow + i * 16) * 32 + rg8]);
      }
#pragma unroll
      for (int i = 0; i < 4; i++)
#pragma unroll
        for (int j = 0; j < 4; j++)
          acc[i][j] = __builtin_amdgcn_mfma_f32_16x16x32_bf16(af[i], bf[j], acc[i][j], 0, 0, 0);
    }
    __syncthreads();
  }

  int ncol = l & 15, mq = (l >> 4) * 4;
#pragma unroll
  for (int i = 0; i < 4; i++) {
#pragma unroll
    for (int j = 0; j < 4; j++) {
      int n = n0 + wn * 64 + j * 16 + ncol;
#pragma unroll
      for (int r = 0; r < 4; r++) {
        int m = m0 + wm * 64 + i * 16 + mq + r;
        int ch = mode ? m : n;
        float val = acc[i][j][r] * bns[ch] + (cb[ch] * bns[ch] + bnt[ch]);
        size_t o;
        if (mode) o = (size_t)(n / NPOS) * ((long)DH * NPOS) + (size_t)m * NPOS + (n % NPOS);
        else      o = (size_t)m * ldc + n;
        C[o] = f2bf(val);
      }
    }
  }
}

// ---------- p-GEMM: C = A[M][K] x B[N][K]^T -> f32 d_out[b][768][49] ----------
template <int SPLN, bool F32OUT>
__global__ __launch_bounds__(256) void k_gemm_flat(
    const u16* __restrict__ A, const u16* __restrict__ B, void* __restrict__ C,
    const float* __restrict__ cb, const float* __restrict__ bns, const float* __restrict__ bnt,
    int K, int NMT, int ldc, long bstride) {
  __shared__ __align__(16) u16 a_lds[2 * 128 * 32];
  __shared__ __align__(16) u16 b_lds[2 * 128 * 32];
  int nwg = gridDim.x, bx = blockIdx.x;
  int wg = ((nwg & 7) == 0) ? ((bx & 7) * (nwg >> 3) + (bx >> 3)) : bx;
  int mt = wg % NMT, nt = wg / NMT;
  int m0 = mt * 128, n0 = nt * 128;
  int tid = threadIdx.x, w = tid >> 6, l = tid & 63;

  int srow = l >> 2;
  int scol = ((l & 3) ^ ((l >> 3) & 3)) * 8;
  const u16* asrc[2]; const u16* bsrc[2];
#pragma unroll
  for (int c = 0; c < 2; c++) {
    int chunk = w * 2 + c;
    asrc[c] = A + (size_t)(m0 + chunk * 16 + srow) * K + scol;
    bsrc[c] = B + (size_t)(n0 + chunk * 16 + srow) * K + scol;
  }
  char* adst = (char*)a_lds + (w * 2) * 1024 + l * 16;
  char* bdst = (char*)b_lds + (w * 2) * 1024 + l * 16;

  f32x4 acc[4][4];
#pragma unroll
  for (int i = 0; i < 4; i++)
#pragma unroll
    for (int j = 0; j < 4; j++) acc[i][j] = (f32x4){0.f, 0.f, 0.f, 0.f};

  int wm = w >> 1, wn = w & 1;
  int rg8 = ((l >> 4) ^ ((l >> 1) & 3)) * 8;
  int arow = wm * 64 + (l & 15);
  int brow = wn * 64 + (l & 15);

  for (int kk = 0; kk < K; kk += 64) {
#pragma unroll
    for (int c = 0; c < 2; c++) {
      GLD16(asrc[c] + kk,      adst + c * 1024);
      GLD16(asrc[c] + kk + 32, adst + 8192 + c * 1024);
      GLD16(bsrc[c] + kk,      bdst + c * 1024);
      GLD16(bsrc[c] + kk + 32, bdst + 8192 + c * 1024);
    }
    __syncthreads();
#pragma unroll
    for (int hf = 0; hf < 2; hf++) {
      const u16* ah = a_lds + hf * (128 * 32);
      const u16* bh = b_lds + hf * (128 * 32);
      s16x8 af[4], bf[4];
#pragma unroll
      for (int i = 0; i < 4; i++) {
        af[i] = *(const s16x8*)(&ah[(arow + i * 16) * 32 + rg8]);
        bf[i] = *(const s16x8*)(&bh[(brow + i * 16) * 32 + rg8]);
      }
#pragma unroll
      for (int i = 0; i < 4; i++)
#pragma unroll
        for (int j = 0; j < 4; j++)
          acc[i][j] = __builtin_amdgcn_mfma_f32_16x16x32_bf16(af[i], bf[j], acc[i][j], 0, 0, 0);
    }
    __syncthreads();
  }

  int ncol = l & 15, mq = (l >> 4) * 4;
#pragma unroll
  for (int i = 0; i < 4; i++) {
#pragma unroll
    for (int j = 0; j < 4; j++) {
      int n = n0 + wn * 64 + j * 16 + ncol;
#pragma unroll
      for (int r = 0; r < 4; r++) {
        int m = m0 + wm * 64 + i * 16 + mq + r;
        int ch = SPLN ? m : n;
        float val = acc[i][j][r] * bns[ch] + (cb[ch] * bns[ch] + bnt[ch]);
        size_t o;
        if (SPLN) o = (size_t)(n / SPLN) * bstride + (size_t)m * SPLN + (n % SPLN);
        else      o = (size_t)m * ldc + n;
        if (F32OUT) ((float*)C)[o] = val;
        else        ((u16*)C)[o] = f2bf(val);
      }
    }
  }
}

// ---------- v_local = BN(dwconv_s2(v4) + b) -> vlT (bf16 [b][49][512]) ----------
__global__ __launch_bounds__(256) void k_dwconv_v(const u16* __restrict__ v4, const float* __restrict__ w,
    const float* __restrict__ bias, const float* __restrict__ bns, const float* __restrict__ bnt,
    u16* __restrict__ vlt) {
  int b = blockIdx.y, ct = blockIdx.x;
  __shared__ u16 tile[64][196];
  int tid = threadIdx.x, wave = tid >> 6, lane = tid & 63;
  const u16* vbp = v4 + ((size_t)b * DH + ct * 64) * NPOS;
  for (int r = wave; r < 64; r += 4) {
    const u16* row = vbp + (size_t)r * NPOS;
    tile[r][lane]       = row[lane];
    tile[r][lane + 64]  = row[lane + 64];
    tile[r][lane + 128] = row[lane + 128];
    if (lane < 4) tile[r][lane + 192] = row[lane + 192];
  }
  __syncthreads();
  for (int idx = tid; idx < 64 * N2; idx += 256) {
    int cl = idx & 63, n2 = idx >> 6;
    int ch = ct * 64 + cl;
    int r = n2 / RES2, s = n2 % RES2;
    float acc = bias[ch];
#pragma unroll
    for (int dy = 0; dy < 3; dy++) {
      int ry = 2 * r - 1 + dy;
      if (ry < 0 || ry >= RES) continue;
#pragma unroll
      for (int dx = 0; dx < 3; dx++) {
        int sx = 2 * s - 1 + dx;
        if (sx < 0 || sx >= RES) continue;
        acc += w[ch * 9 + dy * 3 + dx] * bf2f(tile[cl][ry * RES + sx]);
      }
    }
    vlt[((size_t)b * N2 + n2) * DH + ch] = f2bf(acc * bns[ch] + bnt[ch]);
  }
}

// ---------- MFMA attention per (b,h), LDS = p_lds only (29.7 KB) ----------
// Q/K fragments direct from global (part>=2 lanes zero = K 16->32 pad; OOB rows masked).
// V direct from v4 ([b][512][196] = B-operand rows) as 2x8B. o_lds overlaps p_lds.
__global__ __launch_bounds__(256, 4) void k_attn_mfma(const u16* __restrict__ qT, const u16* __restrict__ kT,
    const u16* __restrict__ v4, const float* __restrict__ bxp, const u16* __restrict__ vlT,
    u16* __restrict__ gT) {
  int h = blockIdx.x, b = blockIdx.y;
  __shared__ __align__(16) u16 p_lds[64 * 232];   // 29,696 B
  float* o_lds = (float*)p_lds;                   // overlap (barrier-protected)
  int tid = threadIdx.x, w = tid >> 6, l = tid & 63;
  int part = l >> 4, row16 = l & 15;
  int mbase = w * 16 + part * 4;
  int ncol = l & 15;

  for (int idx = tid; idx < 64 * 8; idx += 256)
    ((uint*)&p_lds[(idx >> 3) * 232])[104 + (idx & 7)] = 0;

  s16x8 af = (s16x8){0, 0, 0, 0, 0, 0, 0, 0};
  if (part < 2)
    af = *(const s16x8*)(qT + ((size_t)b * N2 + (w * 16 + row16)) * NH_KD + h * 16 + part * 8);

  const u16* kbase = kT + (size_t)b * NPOS * NH_KD + h * 16 + part * 8;
  f32x4 s[13];
#pragma unroll
  for (int f = 0; f < 13; f++) {
    s16x8 bf = (s16x8){0, 0, 0, 0, 0, 0, 0, 0};
    if (part < 2)
      bf = *(const s16x8*)(kbase + (size_t)(f * 16 + row16) * NH_KD);
    s[f] = __builtin_amdgcn_mfma_f32_16x16x32_bf16(af, bf, (f32x4){0.f, 0.f, 0.f, 0.f}, 0, 0, 0);
  }

  const u16* vbase = v4 + ((size_t)b * DH + h * DHEAD) * NPOS;
  int vd = l & 15, vq8 = part * 8;
  auto VLOAD = [&](int f, int kk) {
    const u16* p = vbase + (size_t)(f * 16 + vd) * NPOS + kk + vq8;
    s16x8 r;
    ((u32x2*)&r)[0] = *(const u32x2*)(p);
    ((u32x2*)&r)[1] = *(const u32x2*)(p + 4);
    return r;
  };
  s16x8 vb0[4];
#pragma unroll
  for (int f = 0; f < 4; f++) vb0[f] = VLOAD(f, 0);

#pragma unroll
  for (int q = 0; q < 4; q++) {
    f32x4 bqr[4];
#pragma unroll
    for (int r = 0; r < 4; r++) {
      int mm = mbase + r; if (mm > N2 - 1) mm = N2 - 1;
      bqr[r] = *(const f32x4*)(bxp + (((size_t)h * N2 + mm) * 16 + ncol) * 16 + q * 4);
    }
#pragma unroll
    for (int ff = 0; ff < 4; ff++) {
      int f = q * 4 + ff;
      if (f < 13) {
        int n = f * 16 + ncol;
#pragma unroll
        for (int r = 0; r < 4; r++) {
          int m = mbase + r;
          s[f][r] = (m < N2 && n < NPOS) ? s[f][r] * SCALE_Q + bqr[r][ff] : -1e30f;
        }
      }
    }
  }
#pragma unroll
  for (int r = 0; r < 4; r++) {
    float mx = s[0][r];
#pragma unroll
    for (int f = 1; f < 13; f++) mx = fmaxf(mx, s[f][r]);
    mx = fmaxf(mx, __shfl_xor(mx, 1)); mx = fmaxf(mx, __shfl_xor(mx, 2));
    mx = fmaxf(mx, __shfl_xor(mx, 4)); mx = fmaxf(mx, __shfl_xor(mx, 8));
    float sum = 0.f;
#pragma unroll
    for (int f = 0; f < 13; f++) { s[f][r] = __expf(s[f][r] - mx); sum += s[f][r]; }
    sum += __shfl_xor(sum, 1); sum += __shfl_xor(sum, 2);
    sum += __shfl_xor(sum, 4); sum += __shfl_xor(sum, 8);
    float inv = 1.f / sum;
#pragma unroll
    for (int f = 0; f < 13; f++) s[f][r] *= inv;
  }
#pragma unroll
  for (int f = 0; f < 13; f++) {
    int n = f * 16 + ncol;
#pragma unroll
    for (int r = 0; r < 4; r++)
      p_lds[(mbase + r) * 232 + n] = f2bf(s[f][r]);
  }
  __syncthreads();

  f32x4 o[4];
#pragma unroll
  for (int f = 0; f < 4; f++) o[f] = (f32x4){0.f, 0.f, 0.f, 0.f};
#pragma unroll
  for (int t = 0; t < 7; t++) {
    int kk = t * 32;
    s16x8 vn[4];
    if (t < 6) {
#pragma unroll
      for (int f = 0; f < 4; f++) vn[f] = VLOAD(f, kk + 32);
    }
    s16x8 pa = *(const s16x8*)(&p_lds[(w * 16 + row16) * 232 + kk + part * 8]);
#pragma unroll
    for (int f = 0; f < 4; f++)
      o[f] = __builtin_amdgcn_mfma_f32_16x16x32_bf16(pa, vb0[f], o[f], 0, 0, 0);
    if (t < 6) {
#pragma unroll
      for (int f = 0; f < 4; f++) vb0[f] = vn[f];
    }
  }
  __syncthreads();

#pragma unroll
  for (int f = 0; f < 4; f++)
#pragma unroll
    for (int r = 0; r < 4; r++) {
      int m = mbase + r;
      if (m < N2) o_lds[m * 68 + f * 16 + ncol] = o[f][r];
    }
  __syncthreads();

  for (int idx = tid; idx < N2 * 16; idx += 256) {
    int row = idx >> 4, c4 = (idx & 15) << 2;
    f32x4 ov = *(const f32x4*)(&o_lds[row * 68 + c4]);
    size_t go = ((size_t)b * N2 + row) * DH + h * DHEAD + c4;
    s16x4 vv = *(const s16x4*)(vlT + go);
    s16x4 outv;
#pragma unroll
    for (int e = 0; e < 4; e++) {
      float xv = ov[e] + bf2f((u16)vv[e]);
      float g = 0.5f * xv * (1.f + erff(xv * 0.70710678118f));
      outv[e] = (short)f2bf(g);
    }
    *(s16x4*)(gT + go) = outv;
  }
}

extern "C" void kernel_launch(void* const* d_in, const int* in_sizes, int n_in,
                              void* d_out, int out_size, void* d_ws, size_t ws_size,
                              hipStream_t stream) {
  const float* x   = (const float*)d_in[0];
  const float* qlw = (const float*)d_in[1];
  const float* qlb = (const float*)d_in[2];
  const float* qpw = (const float*)d_in[3];
  const float* qpb = (const float*)d_in[4];
  const float* qbs = (const float*)d_in[5];
  const float* qbt = (const float*)d_in[6];
  const float* kw  = (const float*)d_in[7];
  const float* kb  = (const float*)d_in[8];
  const float* kbs = (const float*)d_in[9];
  const float* kbt = (const float*)d_in[10];
  const float* vw  = (const float*)d_in[11];
  const float* vb  = (const float*)d_in[12];
  const float* vbs = (const float*)d_in[13];
  const float* vbt = (const float*)d_in[14];
  const float* vlw = (const float*)d_in[15];
  const float* vlb = (const float*)d_in[16];
  const float* vls = (const float*)d_in[17];
  const float* vlt_in = (const float*)d_in[18];
  const float* pw  = (const float*)d_in[19];
  const float* pb  = (const float*)d_in[20];
  const float* pbs = (const float*)d_in[21];
  const float* pbt = (const float*)d_in[22];
  const float* ab  = (const float*)d_in[23];
  const int*   bidx = (const int*)d_in[24];
  int noff = in_sizes[23] / NUM_HEADS;

  char* ws = (char*)d_ws;
  size_t off = 0;
  auto alloc = [&](size_t bytes) { char* p = ws + off; off += (bytes + 255) & ~(size_t)255; return p; };
  u16* xbT = (u16*)alloc((size_t)BATCH * NPOS * DIM * 2);      // 77.1 MB (aliased by gT later)
  u16* kTm = (u16*)alloc((size_t)BATCH * NPOS * NH_KD * 2);    // 25.7 MB
  u16* qlT = (u16*)alloc((size_t)BATCH * N2 * DIM * 2);        // 19.3 MB
  u16* qTm = (u16*)alloc((size_t)BATCH * N2 * NH_KD * 2);      //  6.4 MB
  u16* v4m = (u16*)alloc((size_t)BATCH * DH * NPOS * 2);       // 102.8 MB
  u16* vlTm = (u16*)alloc((size_t)BATCH * N2 * DH * 2);        // 25.7 MB  (absorbs attn's OOB V reads)
  float* bxp = (float*)alloc((size_t)NUM_HEADS * N2 * 16 * 16 * 4);  // 0.8 MB
  u16* kwb = (u16*)alloc((size_t)NH_KD * DIM * 2);
  u16* vwb = (u16*)alloc((size_t)DH * DIM * 2);
  u16* qwb = (u16*)alloc((size_t)NH_KD * DIM * 2);
  u16* pwb = (u16*)alloc((size_t)OUT_DIM * DH * 2);
  u16* gTm = xbT;  // alias: all xbT readers complete before k_attn writes gT

  k_prep<<<(788480 + 255) / 256, 256, 0, stream>>>(kw, vw, qpw, pw, ab, bidx, noff,
                                                   kwb, vwb, qwb, pwb, bxp);

  // transpose + fused depthwise q-conv
  k_transpose_dwq<<<dim3(6, BATCH), 256, 0, stream>>>(x, xbT, qlw, qlb, qlT);

  // combined v (3136) + k (784) + q (196) GEMMs, one launch
  k_gemm3<<<4116, 256, 0, stream>>>(xbT, qlT, vwb, kwb, qwb, v4m, kTm, qTm,
                                    vb, vbs, vbt, kb, kbs, kbt, qpb, qbs, qbt);

  k_dwconv_v<<<dim3(8, BATCH), 256, 0, stream>>>(v4m, vlw, vlb, vls, vlt_in, vlTm);
  k_attn_mfma<<<dim3(NUM_HEADS, BATCH), 256, 0, stream>>>(qTm, kTm, v4m, bxp, vlTm, gTm);

  // p: A=pwb[768][512] (m=ch), B=gTm[25088][512] (n=j) -> d_out[b][768][49] f32; 6 x 196
  k_gemm_flat<N2, true><<<1176, 256, 0, stream>>>(
      pwb, gTm, d_out, pb, pbs, pbt, DH, 6, 0, (long)OUT_DIM * N2);
}

// Round 12
// 400.403 us; speedup vs baseline: 1.1284x; 1.1284x over previous
//
#include <hip/hip_runtime.h>
#include <math.h>

#define DIM 384
#define NUM_HEADS 8
#define RES 14
#define RES2 7
#define NPOS 196
#define N2 49
#define DHEAD 64
#define NH_KD 128
#define DH 512
#define OUT_DIM 768
#define BATCH 512
#define SCALE_Q 0.25f

typedef unsigned short u16;
typedef short s16x8 __attribute__((ext_vector_type(8)));
typedef short s16x4 __attribute__((ext_vector_type(4)));
typedef float f32x4 __attribute__((ext_vector_type(4)));
typedef unsigned int u32x2 __attribute__((ext_vector_type(2)));

__device__ __forceinline__ float bf2f(u16 u) {
  union { unsigned int i; float f; } v; v.i = ((unsigned int)u) << 16; return v.f;
}
__device__ __forceinline__ u16 f2bf(float f) {
  union { unsigned int i; float f; } v; v.f = f;
  unsigned int r = v.i + 0x7fffu + ((v.i >> 16) & 1u);
  return (u16)(r >> 16);
}

#define GLD16(gp, lp) __builtin_amdgcn_global_load_lds( \
    (const __attribute__((address_space(1))) void*)(gp), \
    (__attribute__((address_space(3))) void*)(lp), 16, 0, 0)

// ---------- fused prep: weight casts + bias gather in one launch ----------
__global__ __launch_bounds__(256) void k_prep(const float* __restrict__ kw, const float* __restrict__ vw,
                                              const float* __restrict__ qw, const float* __restrict__ pw,
                                              const float* __restrict__ ab, const int* __restrict__ idxs, int noff,
                                              u16* __restrict__ kwb, u16* __restrict__ vwb,
                                              u16* __restrict__ qwb, u16* __restrict__ pwb,
                                              float* __restrict__ bxp) {
  int i = blockIdx.x * 256 + threadIdx.x;
  const int e1 = NH_KD * DIM;                // 49152
  const int e2 = e1 + DH * DIM;              // 245760
  const int e3 = e2 + NH_KD * DIM;           // 294912
  const int e4 = e3 + OUT_DIM * DH;          // 688128
  const int e5 = e4 + NUM_HEADS * N2 * 256;  // 788480
  if (i < e1) kwb[i] = f2bf(kw[i]);
  else if (i < e2) vwb[i - e1] = f2bf(vw[i - e1]);
  else if (i < e3) qwb[i - e2] = f2bf(qw[i - e2]);
  else if (i < e4) pwb[i - e3] = f2bf(pw[i - e3]);
  else if (i < e5) {
    int j = i - e4;
    int f = j & 15, c = (j >> 4) & 15;
    int m = (j >> 8) % N2, h = j / (N2 * 256);
    int n = f * 16 + c;
    bxp[j] = (n < NPOS) ? ab[h * noff + idxs[m * NPOS + n]] : 0.f;
  }
}

// ---------- fused: x transpose (f32 [b][384][196] -> bf16 xbT [b][196][384])
//            + depthwise dwconv_q for this block's 64-channel chunk -> qlT ----------
__global__ __launch_bounds__(256) void k_transpose_dwq(const float* __restrict__ x, u16* __restrict__ xt,
                                                       const float* __restrict__ qlw, const float* __restrict__ qlb,
                                                       u16* __restrict__ qlt) {
  int b = blockIdx.y, c0 = blockIdx.x * 64;
  __shared__ u16 tile[64][196];
  __shared__ float wlds[576];   // 64 ch x 9 taps
  __shared__ float blds[64];
  int tid = threadIdx.x, wave = tid >> 6, lane = tid & 63;
  const float* xb = x + (size_t)b * DIM * NPOS;
  for (int r = wave; r < 64; r += 4) {
    const float* row = xb + (size_t)(c0 + r) * NPOS;
    tile[r][lane]       = f2bf(row[lane]);
    tile[r][lane + 64]  = f2bf(row[lane + 64]);
    tile[r][lane + 128] = f2bf(row[lane + 128]);
    if (lane < 4) tile[r][lane + 192] = f2bf(row[lane + 192]);
  }
  for (int i = tid; i < 576; i += 256) wlds[i] = qlw[c0 * 9 + i];
  if (tid < 64) blds[tid] = qlb[c0 + tid];
  __syncthreads();
  u16* xtb = xt + (size_t)b * NPOS * DIM;
  for (int n = wave; n < NPOS; n += 4)
    xtb[(size_t)n * DIM + c0 + lane] = tile[lane][n];
  for (int idx = tid; idx < 64 * N2; idx += 256) {
    int cl = idx & 63, n2 = idx >> 6;
    int r = n2 / RES2, s = n2 % RES2;
    float acc = blds[cl] + bf2f(tile[cl][(2 * r) * RES + 2 * s]);  // bias + strided residual
#pragma unroll
    for (int dy = 0; dy < 3; dy++) {
      int ry = 2 * r - 1 + dy;
      if (ry < 0 || ry >= RES) continue;
#pragma unroll
      for (int dx = 0; dx < 3; dx++) {
        int sx = 2 * s - 1 + dx;
        if (sx < 0 || sx >= RES) continue;
        acc += wlds[cl * 9 + dy * 3 + dx] * bf2f(tile[cl][ry * RES + sx]);
      }
    }
    qlt[((size_t)b * N2 + n2) * DIM + c0 + cl] = f2bf(acc);
  }
}

// ---------- flattened GEMM: C = A[M][K] x B[N][K]^T, both K-contiguous bf16 ----------
// 128x128 tile, BK=64 (two 8KB 32-K halves/operand, one barrier per 64-K), GLD16 staging.
// chunk = 1KB = 16 rows x 64B; wave w stages chunks w*2, w*2+1.
// Source pre-swizzle (m173/rule21): lane fetches global granule (l&3)^((l>>3)&3);
// frag reads un-swizzle with rg8 = ((l>>4)^((l>>1)&3))*8 -> conflict-free both sides.
// SPLN=0: out[m*ldc + n] (ch=n). SPLN>0: out[(n/SPLN)*bstride + m*SPLN + n%SPLN] (ch=m).
// NOTE (r10/r11 lesson): do NOT merge these GEMMs — shared-input segments with different
// tile->XCD locality thrash L2 (gemm3: 117 -> 185 us, FETCH 2x). Keep separate launches.
template <int SPLN, bool F32OUT>
__global__ __launch_bounds__(256) void k_gemm_flat(
    const u16* __restrict__ A, const u16* __restrict__ B, void* __restrict__ C,
    const float* __restrict__ cb, const float* __restrict__ bns, const float* __restrict__ bnt,
    int K, int NMT, int ldc, long bstride) {
  __shared__ __align__(16) u16 a_lds[2 * 128 * 32];
  __shared__ __align__(16) u16 b_lds[2 * 128 * 32];
  int nwg = gridDim.x, bx = blockIdx.x;
  int wg = ((nwg & 7) == 0) ? ((bx & 7) * (nwg >> 3) + (bx >> 3)) : bx;  // XCD-bijective
  int mt = wg % NMT, nt = wg / NMT;                                      // m fastest: j-tile shared on-XCD
  int m0 = mt * 128, n0 = nt * 128;
  int tid = threadIdx.x, w = tid >> 6, l = tid & 63;

  int srow = l >> 2;
  int scol = ((l & 3) ^ ((l >> 3) & 3)) * 8;   // pre-swizzled source granule
  const u16* asrc[2]; const u16* bsrc[2];
#pragma unroll
  for (int c = 0; c < 2; c++) {
    int chunk = w * 2 + c;
    asrc[c] = A + (size_t)(m0 + chunk * 16 + srow) * K + scol;
    bsrc[c] = B + (size_t)(n0 + chunk * 16 + srow) * K + scol;
  }
  char* adst = (char*)a_lds + (w * 2) * 1024 + l * 16;
  char* bdst = (char*)b_lds + (w * 2) * 1024 + l * 16;

  f32x4 acc[4][4];
#pragma unroll
  for (int i = 0; i < 4; i++)
#pragma unroll
    for (int j = 0; j < 4; j++) acc[i][j] = (f32x4){0.f, 0.f, 0.f, 0.f};

  int wm = w >> 1, wn = w & 1;
  int rg8 = ((l >> 4) ^ ((l >> 1) & 3)) * 8;   // un-swizzling read granule
  int arow = wm * 64 + (l & 15);
  int brow = wn * 64 + (l & 15);

  for (int kk = 0; kk < K; kk += 64) {
#pragma unroll
    for (int c = 0; c < 2; c++) {
      GLD16(asrc[c] + kk,      adst + c * 1024);
      GLD16(asrc[c] + kk + 32, adst + 8192 + c * 1024);
      GLD16(bsrc[c] + kk,      bdst + c * 1024);
      GLD16(bsrc[c] + kk + 32, bdst + 8192 + c * 1024);
    }
    __syncthreads();                 // compiler drains vmcnt before barrier
#pragma unroll
    for (int hf = 0; hf < 2; hf++) {
      const u16* ah = a_lds + hf * (128 * 32);
      const u16* bh = b_lds + hf * (128 * 32);
      s16x8 af[4], bf[4];
#pragma unroll
      for (int i = 0; i < 4; i++) {
        af[i] = *(const s16x8*)(&ah[(arow + i * 16) * 32 + rg8]);
        bf[i] = *(const s16x8*)(&bh[(brow + i * 16) * 32 + rg8]);
      }
#pragma unroll
      for (int i = 0; i < 4; i++)
#pragma unroll
        for (int j = 0; j < 4; j++)
          acc[i][j] = __builtin_amdgcn_mfma_f32_16x16x32_bf16(af[i], bf[j], acc[i][j], 0, 0, 0);
    }
    __syncthreads();
  }

  int ncol = l & 15, mq = (l >> 4) * 4;
#pragma unroll
  for (int i = 0; i < 4; i++) {
#pragma unroll
    for (int j = 0; j < 4; j++) {
      int n = n0 + wn * 64 + j * 16 + ncol;
#pragma unroll
      for (int r = 0; r < 4; r++) {
        int m = m0 + wm * 64 + i * 16 + mq + r;
        int ch = SPLN ? m : n;
        float val = acc[i][j][r] * bns[ch] + (cb[ch] * bns[ch] + bnt[ch]);
        size_t o;
        if (SPLN) o = (size_t)(n / SPLN) * bstride + (size_t)m * SPLN + (n % SPLN);
        else      o = (size_t)m * ldc + n;
        if (F32OUT) ((float*)C)[o] = val;
        else        ((u16*)C)[o] = f2bf(val);
      }
    }
  }
}

// ---------- v_local = BN(dwconv_s2(v4) + b) -> vlT (bf16 [b][49][512]) ----------
__global__ __launch_bounds__(256) void k_dwconv_v(const u16* __restrict__ v4, const float* __restrict__ w,
    const float* __restrict__ bias, const float* __restrict__ bns, const float* __restrict__ bnt,
    u16* __restrict__ vlt) {
  int b = blockIdx.y, ct = blockIdx.x;
  __shared__ u16 tile[64][196];
  int tid = threadIdx.x, wave = tid >> 6, lane = tid & 63;
  const u16* vbp = v4 + ((size_t)b * DH + ct * 64) * NPOS;
  for (int r = wave; r < 64; r += 4) {
    const u16* row = vbp + (size_t)r * NPOS;
    tile[r][lane]       = row[lane];
    tile[r][lane + 64]  = row[lane + 64];
    tile[r][lane + 128] = row[lane + 128];
    if (lane < 4) tile[r][lane + 192] = row[lane + 192];
  }
  __syncthreads();
  for (int idx = tid; idx < 64 * N2; idx += 256) {
    int cl = idx & 63, n2 = idx >> 6;
    int ch = ct * 64 + cl;
    int r = n2 / RES2, s = n2 % RES2;
    float acc = bias[ch];
#pragma unroll
    for (int dy = 0; dy < 3; dy++) {
      int ry = 2 * r - 1 + dy;
      if (ry < 0 || ry >= RES) continue;
#pragma unroll
      for (int dx = 0; dx < 3; dx++) {
        int sx = 2 * s - 1 + dx;
        if (sx < 0 || sx >= RES) continue;
        acc += w[ch * 9 + dy * 3 + dx] * bf2f(tile[cl][ry * RES + sx]);
      }
    }
    vlt[((size_t)b * N2 + n2) * DH + ch] = f2bf(acc * bns[ch] + bnt[ch]);
  }
}

// ---------- MFMA attention per (b,h), LDS = p_lds only (29.7 KB) ----------
// Q/K fragments direct from global (part>=2 lanes zero = K 16->32 pad; OOB rows masked).
// V direct from v4 ([b][512][196] = B-operand rows) as 2x8B. o_lds overlaps p_lds.
__global__ __launch_bounds__(256, 4) void k_attn_mfma(const u16* __restrict__ qT, const u16* __restrict__ kT,
    const u16* __restrict__ v4, const float* __restrict__ bxp, const u16* __restrict__ vlT,
    u16* __restrict__ gT) {
  int h = blockIdx.x, b = blockIdx.y;
  __shared__ __align__(16) u16 p_lds[64 * 232];   // 29,696 B
  float* o_lds = (float*)p_lds;                   // overlap (barrier-protected)
  int tid = threadIdx.x, w = tid >> 6, l = tid & 63;
  int part = l >> 4, row16 = l & 15;
  int mbase = w * 16 + part * 4;
  int ncol = l & 15;

  for (int idx = tid; idx < 64 * 8; idx += 256)
    ((uint*)&p_lds[(idx >> 3) * 232])[104 + (idx & 7)] = 0;

  s16x8 af = (s16x8){0, 0, 0, 0, 0, 0, 0, 0};
  if (part < 2)
    af = *(const s16x8*)(qT + ((size_t)b * N2 + (w * 16 + row16)) * NH_KD + h * 16 + part * 8);

  const u16* kbase = kT + (size_t)b * NPOS * NH_KD + h * 16 + part * 8;
  f32x4 s[13];
#pragma unroll
  for (int f = 0; f < 13; f++) {
    s16x8 bf = (s16x8){0, 0, 0, 0, 0, 0, 0, 0};
    if (part < 2)
      bf = *(const s16x8*)(kbase + (size_t)(f * 16 + row16) * NH_KD);
    s[f] = __builtin_amdgcn_mfma_f32_16x16x32_bf16(af, bf, (f32x4){0.f, 0.f, 0.f, 0.f}, 0, 0, 0);
  }

  const u16* vbase = v4 + ((size_t)b * DH + h * DHEAD) * NPOS;
  int vd = l & 15, vq8 = part * 8;
  auto VLOAD = [&](int f, int kk) {
    const u16* p = vbase + (size_t)(f * 16 + vd) * NPOS + kk + vq8;
    s16x8 r;
    ((u32x2*)&r)[0] = *(const u32x2*)(p);
    ((u32x2*)&r)[1] = *(const u32x2*)(p + 4);
    return r;
  };
  s16x8 vb0[4];
#pragma unroll
  for (int f = 0; f < 4; f++) vb0[f] = VLOAD(f, 0);

#pragma unroll
  for (int q = 0; q < 4; q++) {
    f32x4 bqr[4];
#pragma unroll
    for (int r = 0; r < 4; r++) {
      int mm = mbase + r; if (mm > N2 - 1) mm = N2 - 1;
      bqr[r] = *(const f32x4*)(bxp + (((size_t)h * N2 + mm) * 16 + ncol) * 16 + q * 4);
    }
#pragma unroll
    for (int ff = 0; ff < 4; ff++) {
      int f = q * 4 + ff;
      if (f < 13) {
        int n = f * 16 + ncol;
#pragma unroll
        for (int r = 0; r < 4; r++) {
          int m = mbase + r;
          s[f][r] = (m < N2 && n < NPOS) ? s[f][r] * SCALE_Q + bqr[r][ff] : -1e30f;
        }
      }
    }
  }
#pragma unroll
  for (int r = 0; r < 4; r++) {
    float mx = s[0][r];
#pragma unroll
    for (int f = 1; f < 13; f++) mx = fmaxf(mx, s[f][r]);
    mx = fmaxf(mx, __shfl_xor(mx, 1)); mx = fmaxf(mx, __shfl_xor(mx, 2));
    mx = fmaxf(mx, __shfl_xor(mx, 4)); mx = fmaxf(mx, __shfl_xor(mx, 8));
    float sum = 0.f;
#pragma unroll
    for (int f = 0; f < 13; f++) { s[f][r] = __expf(s[f][r] - mx); sum += s[f][r]; }
    sum += __shfl_xor(sum, 1); sum += __shfl_xor(sum, 2);
    sum += __shfl_xor(sum, 4); sum += __shfl_xor(sum, 8);
    float inv = 1.f / sum;
#pragma unroll
    for (int f = 0; f < 13; f++) s[f][r] *= inv;
  }
#pragma unroll
  for (int f = 0; f < 13; f++) {
    int n = f * 16 + ncol;
#pragma unroll
    for (int r = 0; r < 4; r++)
      p_lds[(mbase + r) * 232 + n] = f2bf(s[f][r]);
  }
  __syncthreads();

  f32x4 o[4];
#pragma unroll
  for (int f = 0; f < 4; f++) o[f] = (f32x4){0.f, 0.f, 0.f, 0.f};
#pragma unroll
  for (int t = 0; t < 7; t++) {
    int kk = t * 32;
    s16x8 vn[4];
    if (t < 6) {
#pragma unroll
      for (int f = 0; f < 4; f++) vn[f] = VLOAD(f, kk + 32);
    }
    s16x8 pa = *(const s16x8*)(&p_lds[(w * 16 + row16) * 232 + kk + part * 8]);
#pragma unroll
    for (int f = 0; f < 4; f++)
      o[f] = __builtin_amdgcn_mfma_f32_16x16x32_bf16(pa, vb0[f], o[f], 0, 0, 0);
    if (t < 6) {
#pragma unroll
      for (int f = 0; f < 4; f++) vb0[f] = vn[f];
    }
  }
  __syncthreads();

#pragma unroll
  for (int f = 0; f < 4; f++)
#pragma unroll
    for (int r = 0; r < 4; r++) {
      int m = mbase + r;
      if (m < N2) o_lds[m * 68 + f * 16 + ncol] = o[f][r];
    }
  __syncthreads();

  for (int idx = tid; idx < N2 * 16; idx += 256) {
    int row = idx >> 4, c4 = (idx & 15) << 2;
    f32x4 ov = *(const f32x4*)(&o_lds[row * 68 + c4]);
    size_t go = ((size_t)b * N2 + row) * DH + h * DHEAD + c4;
    s16x4 vv = *(const s16x4*)(vlT + go);
    s16x4 outv;
#pragma unroll
    for (int e = 0; e < 4; e++) {
      float xv = ov[e] + bf2f((u16)vv[e]);
      float g = 0.5f * xv * (1.f + erff(xv * 0.70710678118f));
      outv[e] = (short)f2bf(g);
    }
    *(s16x4*)(gT + go) = outv;
  }
}

extern "C" void kernel_launch(void* const* d_in, const int* in_sizes, int n_in,
                              void* d_out, int out_size, void* d_ws, size_t ws_size,
                              hipStream_t stream) {
  const float* x   = (const float*)d_in[0];
  const float* qlw = (const float*)d_in[1];
  const float* qlb = (const float*)d_in[2];
  const float* qpw = (const float*)d_in[3];
  const float* qpb = (const float*)d_in[4];
  const float* qbs = (const float*)d_in[5];
  const float* qbt = (const float*)d_in[6];
  const float* kw  = (const float*)d_in[7];
  const float* kb  = (const float*)d_in[8];
  const float* kbs = (const float*)d_in[9];
  const float* kbt = (const float*)d_in[10];
  const float* vw  = (const float*)d_in[11];
  const float* vb  = (const float*)d_in[12];
  const float* vbs = (const float*)d_in[13];
  const float* vbt = (const float*)d_in[14];
  const float* vlw = (const float*)d_in[15];
  const float* vlb = (const float*)d_in[16];
  const float* vls = (const float*)d_in[17];
  const float* vlt_in = (const float*)d_in[18];
  const float* pw  = (const float*)d_in[19];
  const float* pb  = (const float*)d_in[20];
  const float* pbs = (const float*)d_in[21];
  const float* pbt = (const float*)d_in[22];
  const float* ab  = (const float*)d_in[23];
  const int*   bidx = (const int*)d_in[24];
  int noff = in_sizes[23] / NUM_HEADS;

  char* ws = (char*)d_ws;
  size_t off = 0;
  auto alloc = [&](size_t bytes) { char* p = ws + off; off += (bytes + 255) & ~(size_t)255; return p; };
  u16* xbT = (u16*)alloc((size_t)BATCH * NPOS * DIM * 2);      // 77.1 MB (aliased by gT later)
  u16* kTm = (u16*)alloc((size_t)BATCH * NPOS * NH_KD * 2);    // 25.7 MB
  u16* qlT = (u16*)alloc((size_t)BATCH * N2 * DIM * 2);        // 19.3 MB
  u16* qTm = (u16*)alloc((size_t)BATCH * N2 * NH_KD * 2);      //  6.4 MB
  u16* v4m = (u16*)alloc((size_t)BATCH * DH * NPOS * 2);       // 102.8 MB
  u16* vlTm = (u16*)alloc((size_t)BATCH * N2 * DH * 2);        // 25.7 MB  (absorbs attn's OOB V reads)
  float* bxp = (float*)alloc((size_t)NUM_HEADS * N2 * 16 * 16 * 4);  // 0.8 MB
  u16* kwb = (u16*)alloc((size_t)NH_KD * DIM * 2);
  u16* vwb = (u16*)alloc((size_t)DH * DIM * 2);
  u16* qwb = (u16*)alloc((size_t)NH_KD * DIM * 2);
  u16* pwb = (u16*)alloc((size_t)OUT_DIM * DH * 2);
  u16* gTm = xbT;  // alias: all xbT readers complete before k_attn writes gT

  k_prep<<<(788480 + 255) / 256, 256, 0, stream>>>(kw, vw, qpw, pw, ab, bidx, noff,
                                                   kwb, vwb, qwb, pwb, bxp);

  // transpose + fused depthwise q-conv
  k_transpose_dwq<<<dim3(6, BATCH), 256, 0, stream>>>(x, xbT, qlw, qlb, qlT);

  // k: A=xbT[100352][384] (m=j), B=kwb[128][384] (n=ch) -> kTm[j][128]; 784 m-tiles x 1 n-tile
  k_gemm_flat<0, false><<<784, 256, 0, stream>>>(
      xbT, kwb, kTm, kb, kbs, kbt, DIM, 784, NH_KD, 0);
  // v: A=vwb[512][384] (m=ch), B=xbT (n=j) -> v4m[b][512][196]; 4 m-tiles x 784 n-tiles
  k_gemm_flat<NPOS, false><<<3136, 256, 0, stream>>>(
      vwb, xbT, v4m, vb, vbs, vbt, DIM, 4, 0, (long)DH * NPOS);
  // q: A=qlT[25088][384] (m=j), B=qwb (n=ch) -> qTm[j][128]; 196 m-tiles x 1 n-tile
  k_gemm_flat<0, false><<<196, 256, 0, stream>>>(
      qlT, qwb, qTm, qpb, qbs, qbt, DIM, 196, NH_KD, 0);

  k_dwconv_v<<<dim3(8, BATCH), 256, 0, stream>>>(v4m, vlw, vlb, vls, vlt_in, vlTm);
  k_attn_mfma<<<dim3(NUM_HEADS, BATCH), 256, 0, stream>>>(qTm, kTm, v4m, bxp, vlTm, gTm);

  // p: A=pwb[768][512] (m=ch), B=gTm[25088][512] (n=j) -> d_out[b][768][49] f32; 6 x 196
  k_gemm_flat<N2, true><<<1176, 256, 0, stream>>>(
      pwb, gTm, d_out, pb, pbs, pbt, DH, 6, 0, (long)OUT_DIM * N2);
}

// Round 13
// 395.740 us; speedup vs baseline: 1.1417x; 1.0118x over previous
//
#include <hip/hip_runtime.h>
#include <math.h>

#define DIM 384
#define NUM_HEADS 8
#define RES 14
#define RES2 7
#define NPOS 196
#define N2 49
#define DHEAD 64
#define NH_KD 128
#define DH 512
#define OUT_DIM 768
#define BATCH 512
#define SCALE_Q 0.25f

typedef unsigned short u16;
typedef short s16x8 __attribute__((ext_vector_type(8)));
typedef short s16x4 __attribute__((ext_vector_type(4)));
typedef float f32x4 __attribute__((ext_vector_type(4)));
typedef unsigned int u32x2 __attribute__((ext_vector_type(2)));

__device__ __forceinline__ float bf2f(u16 u) {
  union { unsigned int i; float f; } v; v.i = ((unsigned int)u) << 16; return v.f;
}
__device__ __forceinline__ u16 f2bf(float f) {
  union { unsigned int i; float f; } v; v.f = f;
  unsigned int r = v.i + 0x7fffu + ((v.i >> 16) & 1u);
  return (u16)(r >> 16);
}

#define GLD16(gp, lp) __builtin_amdgcn_global_load_lds( \
    (const __attribute__((address_space(1))) void*)(gp), \
    (__attribute__((address_space(3))) void*)(lp), 16, 0, 0)

// ---------- fused prep: weight casts + bias gather in one launch ----------
__global__ __launch_bounds__(256) void k_prep(const float* __restrict__ kw, const float* __restrict__ vw,
                                              const float* __restrict__ qw, const float* __restrict__ pw,
                                              const float* __restrict__ ab, const int* __restrict__ idxs, int noff,
                                              u16* __restrict__ kwb, u16* __restrict__ vwb,
                                              u16* __restrict__ qwb, u16* __restrict__ pwb,
                                              float* __restrict__ bxp) {
  int i = blockIdx.x * 256 + threadIdx.x;
  const int e1 = NH_KD * DIM;                // 49152
  const int e2 = e1 + DH * DIM;              // 245760
  const int e3 = e2 + NH_KD * DIM;           // 294912
  const int e4 = e3 + OUT_DIM * DH;          // 688128
  const int e5 = e4 + NUM_HEADS * N2 * 256;  // 788480
  if (i < e1) kwb[i] = f2bf(kw[i]);
  else if (i < e2) vwb[i - e1] = f2bf(vw[i - e1]);
  else if (i < e3) qwb[i - e2] = f2bf(qw[i - e2]);
  else if (i < e4) pwb[i - e3] = f2bf(pw[i - e3]);
  else if (i < e5) {
    int j = i - e4;
    int f = j & 15, c = (j >> 4) & 15;
    int m = (j >> 8) % N2, h = j / (N2 * 256);
    int n = f * 16 + c;
    bxp[j] = (n < NPOS) ? ab[h * noff + idxs[m * NPOS + n]] : 0.f;
  }
}

// ---------- fused transpose + depthwise dwconv_q, transposed-tile layout ----------
// tileT[196 pos][70 ch-stride] u16: dword stride 35 (== 3 mod 32) -> every phase's
// access pattern is <=2-way bank aliased (free, m136):
//  ph1 writes tileT[n][r]: banks 3n mod 32 over lanes -> 2-way.
//  ph2 reads 4ch/lane (2x b32): banks 3n + 2g, n-groups mix parity -> 2-way; 8B stores.
//  ph3 reads 2ch/lane (b32): banks cp + 3*pos -> 2-way; weights wlds2[tap][64ch] f32
//      consecutive-pair reads; packed 4B qlT stores.
__global__ __launch_bounds__(256) void k_transpose_dwq(const float* __restrict__ x, u16* __restrict__ xt,
                                                       const float* __restrict__ qlw, const float* __restrict__ qlb,
                                                       u16* __restrict__ qlt) {
  int b = blockIdx.y, c0 = blockIdx.x * 64;
  __shared__ __align__(8) u16 tileT[196 * 70];   // 27,440 B
  __shared__ float wlds2[576];                   // [tap][64 ch]
  __shared__ float blds[64];
  int tid = threadIdx.x, wave = tid >> 6, lane = tid & 63;
  const float* xb = x + (size_t)b * DIM * NPOS;
  for (int r = wave; r < 64; r += 4) {
    const float* row = xb + (size_t)(c0 + r) * NPOS;
    tileT[lane * 70 + r]         = f2bf(row[lane]);
    tileT[(lane + 64) * 70 + r]  = f2bf(row[lane + 64]);
    tileT[(lane + 128) * 70 + r] = f2bf(row[lane + 128]);
    if (lane < 4) tileT[(lane + 192) * 70 + r] = f2bf(row[lane + 192]);
  }
  for (int i = tid; i < 576; i += 256) {
    int c = i / 9, t = i % 9;
    wlds2[t * 64 + c] = qlw[(size_t)(c0 + c) * 9 + t];
  }
  if (tid < 64) blds[tid] = qlb[c0 + tid];
  __syncthreads();

  // phase 2: xbT write, 4 channels per lane, 8B vector stores
  u16* xtb = xt + (size_t)b * NPOS * DIM + c0;
  for (int idx = tid; idx < NPOS * 16; idx += 256) {
    int n = idx >> 4, g = (idx & 15) << 2;
    u32x2 val;
    val[0] = *(const uint*)&tileT[n * 70 + g];
    val[1] = *(const uint*)&tileT[n * 70 + g + 2];
    *(u32x2*)(xtb + (size_t)n * DIM + g) = val;
  }
  // phase 3: dwconv, 2 channels per lane, packed 4B stores
  u16* qb = qlt + (size_t)b * N2 * DIM + c0;
  for (int idx = tid; idx < N2 * 32; idx += 256) {
    int cp = idx & 31, n2 = idx >> 5;
    int c = cp << 1;
    int r = n2 / RES2, s = n2 % RES2;
    uint rv = *(const uint*)&tileT[((2 * r) * RES + 2 * s) * 70 + c];
    float a0 = blds[c]     + bf2f((u16)(rv & 0xffff));
    float a1 = blds[c + 1] + bf2f((u16)(rv >> 16));
#pragma unroll
    for (int dy = 0; dy < 3; dy++) {
      int ry = 2 * r - 1 + dy;
      if (ry < 0 || ry >= RES) continue;
#pragma unroll
      for (int dx = 0; dx < 3; dx++) {
        int sx = 2 * s - 1 + dx;
        if (sx < 0 || sx >= RES) continue;
        uint tv = *(const uint*)&tileT[(ry * RES + sx) * 70 + c];
        int t = dy * 3 + dx;
        a0 += wlds2[t * 64 + c]     * bf2f((u16)(tv & 0xffff));
        a1 += wlds2[t * 64 + c + 1] * bf2f((u16)(tv >> 16));
      }
    }
    uint outp = (uint)f2bf(a0) | ((uint)f2bf(a1) << 16);
    *(uint*)(qb + (size_t)n2 * DIM + c) = outp;
  }
}

// ---------- flattened GEMM: C = A[M][K] x B[N][K]^T, both K-contiguous bf16 ----------
// 128x128 tile, BK=64 (two 8KB 32-K halves/operand, one barrier per 64-K), GLD16 staging.
// chunk = 1KB = 16 rows x 64B; wave w stages chunks w*2, w*2+1.
// Source pre-swizzle (m173/rule21): lane fetches global granule (l&3)^((l>>3)&3);
// frag reads un-swizzle with rg8 = ((l>>4)^((l>>1)&3))*8 -> conflict-free both sides.
// SPLN=0: out[m*ldc + n] (ch=n). SPLN>0: out[(n/SPLN)*bstride + m*SPLN + n%SPLN] (ch=m).
// NOTE (r10/r11 lesson): do NOT merge these GEMMs — shared-input segments with different
// tile->XCD locality thrash L2 (gemm3: 117 -> 185 us, FETCH 2x). Keep separate launches.
template <int SPLN, bool F32OUT>
__global__ __launch_bounds__(256) void k_gemm_flat(
    const u16* __restrict__ A, const u16* __restrict__ B, void* __restrict__ C,
    const float* __restrict__ cb, const float* __restrict__ bns, const float* __restrict__ bnt,
    int K, int NMT, int ldc, long bstride) {
  __shared__ __align__(16) u16 a_lds[2 * 128 * 32];
  __shared__ __align__(16) u16 b_lds[2 * 128 * 32];
  int nwg = gridDim.x, bx = blockIdx.x;
  int wg = ((nwg & 7) == 0) ? ((bx & 7) * (nwg >> 3) + (bx >> 3)) : bx;  // XCD-bijective
  int mt = wg % NMT, nt = wg / NMT;                                      // m fastest: j-tile shared on-XCD
  int m0 = mt * 128, n0 = nt * 128;
  int tid = threadIdx.x, w = tid >> 6, l = tid & 63;

  int srow = l >> 2;
  int scol = ((l & 3) ^ ((l >> 3) & 3)) * 8;   // pre-swizzled source granule
  const u16* asrc[2]; const u16* bsrc[2];
#pragma unroll
  for (int c = 0; c < 2; c++) {
    int chunk = w * 2 + c;
    asrc[c] = A + (size_t)(m0 + chunk * 16 + srow) * K + scol;
    bsrc[c] = B + (size_t)(n0 + chunk * 16 + srow) * K + scol;
  }
  char* adst = (char*)a_lds + (w * 2) * 1024 + l * 16;
  char* bdst = (char*)b_lds + (w * 2) * 1024 + l * 16;

  f32x4 acc[4][4];
#pragma unroll
  for (int i = 0; i < 4; i++)
#pragma unroll
    for (int j = 0; j < 4; j++) acc[i][j] = (f32x4){0.f, 0.f, 0.f, 0.f};

  int wm = w >> 1, wn = w & 1;
  int rg8 = ((l >> 4) ^ ((l >> 1) & 3)) * 8;   // un-swizzling read granule
  int arow = wm * 64 + (l & 15);
  int brow = wn * 64 + (l & 15);

  for (int kk = 0; kk < K; kk += 64) {
#pragma unroll
    for (int c = 0; c < 2; c++) {
      GLD16(asrc[c] + kk,      adst + c * 1024);
      GLD16(asrc[c] + kk + 32, adst + 8192 + c * 1024);
      GLD16(bsrc[c] + kk,      bdst + c * 1024);
      GLD16(bsrc[c] + kk + 32, bdst + 8192 + c * 1024);
    }
    __syncthreads();                 // compiler drains vmcnt before barrier
#pragma unroll
    for (int hf = 0; hf < 2; hf++) {
      const u16* ah = a_lds + hf * (128 * 32);
      const u16* bh = b_lds + hf * (128 * 32);
      s16x8 af[4], bf[4];
#pragma unroll
      for (int i = 0; i < 4; i++) {
        af[i] = *(const s16x8*)(&ah[(arow + i * 16) * 32 + rg8]);
        bf[i] = *(const s16x8*)(&bh[(brow + i * 16) * 32 + rg8]);
      }
#pragma unroll
      for (int i = 0; i < 4; i++)
#pragma unroll
        for (int j = 0; j < 4; j++)
          acc[i][j] = __builtin_amdgcn_mfma_f32_16x16x32_bf16(af[i], bf[j], acc[i][j], 0, 0, 0);
    }
    __syncthreads();
  }

  int ncol = l & 15, mq = (l >> 4) * 4;
#pragma unroll
  for (int i = 0; i < 4; i++) {
#pragma unroll
    for (int j = 0; j < 4; j++) {
      int n = n0 + wn * 64 + j * 16 + ncol;
#pragma unroll
      for (int r = 0; r < 4; r++) {
        int m = m0 + wm * 64 + i * 16 + mq + r;
        int ch = SPLN ? m : n;
        float val = acc[i][j][r] * bns[ch] + (cb[ch] * bns[ch] + bnt[ch]);
        size_t o;
        if (SPLN) o = (size_t)(n / SPLN) * bstride + (size_t)m * SPLN + (n % SPLN);
        else      o = (size_t)m * ldc + n;
        if (F32OUT) ((float*)C)[o] = val;
        else        ((u16*)C)[o] = f2bf(val);
      }
    }
  }
}

// ---------- v_local = BN(dwconv_s2(v4) + b) -> vlT (bf16 [b][49][512]) ----------
__global__ __launch_bounds__(256) void k_dwconv_v(const u16* __restrict__ v4, const float* __restrict__ w,
    const float* __restrict__ bias, const float* __restrict__ bns, const float* __restrict__ bnt,
    u16* __restrict__ vlt) {
  int b = blockIdx.y, ct = blockIdx.x;
  __shared__ u16 tile[64][196];
  int tid = threadIdx.x, wave = tid >> 6, lane = tid & 63;
  const u16* vbp = v4 + ((size_t)b * DH + ct * 64) * NPOS;
  for (int r = wave; r < 64; r += 4) {
    const u16* row = vbp + (size_t)r * NPOS;
    tile[r][lane]       = row[lane];
    tile[r][lane + 64]  = row[lane + 64];
    tile[r][lane + 128] = row[lane + 128];
    if (lane < 4) tile[r][lane + 192] = row[lane + 192];
  }
  __syncthreads();
  for (int idx = tid; idx < 64 * N2; idx += 256) {
    int cl = idx & 63, n2 = idx >> 6;
    int ch = ct * 64 + cl;
    int r = n2 / RES2, s = n2 % RES2;
    float acc = bias[ch];
#pragma unroll
    for (int dy = 0; dy < 3; dy++) {
      int ry = 2 * r - 1 + dy;
      if (ry < 0 || ry >= RES) continue;
#pragma unroll
      for (int dx = 0; dx < 3; dx++) {
        int sx = 2 * s - 1 + dx;
        if (sx < 0 || sx >= RES) continue;
        acc += w[ch * 9 + dy * 3 + dx] * bf2f(tile[cl][ry * RES + sx]);
      }
    }
    vlt[((size_t)b * N2 + n2) * DH + ch] = f2bf(acc * bns[ch] + bnt[ch]);
  }
}

// ---------- MFMA attention per (b,h), LDS = p_lds only (29.7 KB) ----------
// Q/K fragments direct from global (part>=2 lanes zero = K 16->32 pad; OOB rows masked).
// V direct from v4 ([b][512][196] = B-operand rows) as 2x8B. o_lds overlaps p_lds.
__global__ __launch_bounds__(256, 4) void k_attn_mfma(const u16* __restrict__ qT, const u16* __restrict__ kT,
    const u16* __restrict__ v4, const float* __restrict__ bxp, const u16* __restrict__ vlT,
    u16* __restrict__ gT) {
  int h = blockIdx.x, b = blockIdx.y;
  __shared__ __align__(16) u16 p_lds[64 * 232];   // 29,696 B
  float* o_lds = (float*)p_lds;                   // overlap (barrier-protected)
  int tid = threadIdx.x, w = tid >> 6, l = tid & 63;
  int part = l >> 4, row16 = l & 15;
  int mbase = w * 16 + part * 4;
  int ncol = l & 15;

  for (int idx = tid; idx < 64 * 8; idx += 256)
    ((uint*)&p_lds[(idx >> 3) * 232])[104 + (idx & 7)] = 0;

  s16x8 af = (s16x8){0, 0, 0, 0, 0, 0, 0, 0};
  if (part < 2)
    af = *(const s16x8*)(qT + ((size_t)b * N2 + (w * 16 + row16)) * NH_KD + h * 16 + part * 8);

  const u16* kbase = kT + (size_t)b * NPOS * NH_KD + h * 16 + part * 8;
  f32x4 s[13];
#pragma unroll
  for (int f = 0; f < 13; f++) {
    s16x8 bf = (s16x8){0, 0, 0, 0, 0, 0, 0, 0};
    if (part < 2)
      bf = *(const s16x8*)(kbase + (size_t)(f * 16 + row16) * NH_KD);
    s[f] = __builtin_amdgcn_mfma_f32_16x16x32_bf16(af, bf, (f32x4){0.f, 0.f, 0.f, 0.f}, 0, 0, 0);
  }

  const u16* vbase = v4 + ((size_t)b * DH + h * DHEAD) * NPOS;
  int vd = l & 15, vq8 = part * 8;
  auto VLOAD = [&](int f, int kk) {
    const u16* p = vbase + (size_t)(f * 16 + vd) * NPOS + kk + vq8;
    s16x8 r;
    ((u32x2*)&r)[0] = *(const u32x2*)(p);
    ((u32x2*)&r)[1] = *(const u32x2*)(p + 4);
    return r;
  };
  s16x8 vb0[4];
#pragma unroll
  for (int f = 0; f < 4; f++) vb0[f] = VLOAD(f, 0);

#pragma unroll
  for (int q = 0; q < 4; q++) {
    f32x4 bqr[4];
#pragma unroll
    for (int r = 0; r < 4; r++) {
      int mm = mbase + r; if (mm > N2 - 1) mm = N2 - 1;
      bqr[r] = *(const f32x4*)(bxp + (((size_t)h * N2 + mm) * 16 + ncol) * 16 + q * 4);
    }
#pragma unroll
    for (int ff = 0; ff < 4; ff++) {
      int f = q * 4 + ff;
      if (f < 13) {
        int n = f * 16 + ncol;
#pragma unroll
        for (int r = 0; r < 4; r++) {
          int m = mbase + r;
          s[f][r] = (m < N2 && n < NPOS) ? s[f][r] * SCALE_Q + bqr[r][ff] : -1e30f;
        }
      }
    }
  }
#pragma unroll
  for (int r = 0; r < 4; r++) {
    float mx = s[0][r];
#pragma unroll
    for (int f = 1; f < 13; f++) mx = fmaxf(mx, s[f][r]);
    mx = fmaxf(mx, __shfl_xor(mx, 1)); mx = fmaxf(mx, __shfl_xor(mx, 2));
    mx = fmaxf(mx, __shfl_xor(mx, 4)); mx = fmaxf(mx, __shfl_xor(mx, 8));
    float sum = 0.f;
#pragma unroll
    for (int f = 0; f < 13; f++) { s[f][r] = __expf(s[f][r] - mx); sum += s[f][r]; }
    sum += __shfl_xor(sum, 1); sum += __shfl_xor(sum, 2);
    sum += __shfl_xor(sum, 4); sum += __shfl_xor(sum, 8);
    float inv = 1.f / sum;
#pragma unroll
    for (int f = 0; f < 13; f++) s[f][r] *= inv;
  }
#pragma unroll
  for (int f = 0; f < 13; f++) {
    int n = f * 16 + ncol;
#pragma unroll
    for (int r = 0; r < 4; r++)
      p_lds[(mbase + r) * 232 + n] = f2bf(s[f][r]);
  }
  __syncthreads();

  f32x4 o[4];
#pragma unroll
  for (int f = 0; f < 4; f++) o[f] = (f32x4){0.f, 0.f, 0.f, 0.f};
#pragma unroll
  for (int t = 0; t < 7; t++) {
    int kk = t * 32;
    s16x8 vn[4];
    if (t < 6) {
#pragma unroll
      for (int f = 0; f < 4; f++) vn[f] = VLOAD(f, kk + 32);
    }
    s16x8 pa = *(const s16x8*)(&p_lds[(w * 16 + row16) * 232 + kk + part * 8]);
#pragma unroll
    for (int f = 0; f < 4; f++)
      o[f] = __builtin_amdgcn_mfma_f32_16x16x32_bf16(pa, vb0[f], o[f], 0, 0, 0);
    if (t < 6) {
#pragma unroll
      for (int f = 0; f < 4; f++) vb0[f] = vn[f];
    }
  }
  __syncthreads();

#pragma unroll
  for (int f = 0; f < 4; f++)
#pragma unroll
    for (int r = 0; r < 4; r++) {
      int m = mbase + r;
      if (m < N2) o_lds[m * 68 + f * 16 + ncol] = o[f][r];
    }
  __syncthreads();

  for (int idx = tid; idx < N2 * 16; idx += 256) {
    int row = idx >> 4, c4 = (idx & 15) << 2;
    f32x4 ov = *(const f32x4*)(&o_lds[row * 68 + c4]);
    size_t go = ((size_t)b * N2 + row) * DH + h * DHEAD + c4;
    s16x4 vv = *(const s16x4*)(vlT + go);
    s16x4 outv;
#pragma unroll
    for (int e = 0; e < 4; e++) {
      float xv = ov[e] + bf2f((u16)vv[e]);
      float g = 0.5f * xv * (1.f + erff(xv * 0.70710678118f));
      outv[e] = (short)f2bf(g);
    }
    *(s16x4*)(gT + go) = outv;
  }
}

extern "C" void kernel_launch(void* const* d_in, const int* in_sizes, int n_in,
                              void* d_out, int out_size, void* d_ws, size_t ws_size,
                              hipStream_t stream) {
  const float* x   = (const float*)d_in[0];
  const float* qlw = (const float*)d_in[1];
  const float* qlb = (const float*)d_in[2];
  const float* qpw = (const float*)d_in[3];
  const float* qpb = (const float*)d_in[4];
  const float* qbs = (const float*)d_in[5];
  const float* qbt = (const float*)d_in[6];
  const float* kw  = (const float*)d_in[7];
  const float* kb  = (const float*)d_in[8];
  const float* kbs = (const float*)d_in[9];
  const float* kbt = (const float*)d_in[10];
  const float* vw  = (const float*)d_in[11];
  const float* vb  = (const float*)d_in[12];
  const float* vbs = (const float*)d_in[13];
  const float* vbt = (const float*)d_in[14];
  const float* vlw = (const float*)d_in[15];
  const float* vlb = (const float*)d_in[16];
  const float* vls = (const float*)d_in[17];
  const float* vlt_in = (const float*)d_in[18];
  const float* pw  = (const float*)d_in[19];
  const float* pb  = (const float*)d_in[20];
  const float* pbs = (const float*)d_in[21];
  const float* pbt = (const float*)d_in[22];
  const float* ab  = (const float*)d_in[23];
  const int*   bidx = (const int*)d_in[24];
  int noff = in_sizes[23] / NUM_HEADS;

  char* ws = (char*)d_ws;
  size_t off = 0;
  auto alloc = [&](size_t bytes) { char* p = ws + off; off += (bytes + 255) & ~(size_t)255; return p; };
  u16* xbT = (u16*)alloc((size_t)BATCH * NPOS * DIM * 2);      // 77.1 MB (aliased by gT later)
  u16* kTm = (u16*)alloc((size_t)BATCH * NPOS * NH_KD * 2);    // 25.7 MB
  u16* qlT = (u16*)alloc((size_t)BATCH * N2 * DIM * 2);        // 19.3 MB
  u16* qTm = (u16*)alloc((size_t)BATCH * N2 * NH_KD * 2);      //  6.4 MB
  u16* v4m = (u16*)alloc((size_t)BATCH * DH * NPOS * 2);       // 102.8 MB
  u16* vlTm = (u16*)alloc((size_t)BATCH * N2 * DH * 2);        // 25.7 MB  (absorbs attn's OOB V reads)
  float* bxp = (float*)alloc((size_t)NUM_HEADS * N2 * 16 * 16 * 4);  // 0.8 MB
  u16* kwb = (u16*)alloc((size_t)NH_KD * DIM * 2);
  u16* vwb = (u16*)alloc((size_t)DH * DIM * 2);
  u16* qwb = (u16*)alloc((size_t)NH_KD * DIM * 2);
  u16* pwb = (u16*)alloc((size_t)OUT_DIM * DH * 2);
  u16* gTm = xbT;  // alias: all xbT readers complete before k_attn writes gT

  k_prep<<<(788480 + 255) / 256, 256, 0, stream>>>(kw, vw, qpw, pw, ab, bidx, noff,
                                                   kwb, vwb, qwb, pwb, bxp);

  // transpose + fused depthwise q-conv (transposed-tile layout)
  k_transpose_dwq<<<dim3(6, BATCH), 256, 0, stream>>>(x, xbT, qlw, qlb, qlT);

  // k: A=xbT[100352][384] (m=j), B=kwb[128][384] (n=ch) -> kTm[j][128]; 784 m-tiles x 1 n-tile
  k_gemm_flat<0, false><<<784, 256, 0, stream>>>(
      xbT, kwb, kTm, kb, kbs, kbt, DIM, 784, NH_KD, 0);
  // v: A=vwb[512][384] (m=ch), B=xbT (n=j) -> v4m[b][512][196]; 4 m-tiles x 784 n-tiles
  k_gemm_flat<NPOS, false><<<3136, 256, 0, stream>>>(
      vwb, xbT, v4m, vb, vbs, vbt, DIM, 4, 0, (long)DH * NPOS);
  // q: A=qlT[25088][384] (m=j), B=qwb (n=ch) -> qTm[j][128]; 196 m-tiles x 1 n-tile
  k_gemm_flat<0, false><<<196, 256, 0, stream>>>(
      qlT, qwb, qTm, qpb, qbs, qbt, DIM, 196, NH_KD, 0);

  k_dwconv_v<<<dim3(8, BATCH), 256, 0, stream>>>(v4m, vlw, vlb, vls, vlt_in, vlTm);
  k_attn_mfma<<<dim3(NUM_HEADS, BATCH), 256, 0, stream>>>(qTm, kTm, v4m, bxp, vlTm, gTm);

  // p: A=pwb[768][512] (m=ch), B=gTm[25088][512] (n=j) -> d_out[b][768][49] f32; 6 x 196
  k_gemm_flat<N2, true><<<1176, 256, 0, stream>>>(
      pwb, gTm, d_out, pb, pbs, pbt, DH, 6, 0, (long)OUT_DIM * N2);
}

// Round 14
// 379.497 us; speedup vs baseline: 1.1906x; 1.0428x over previous
//
#include <hip/hip_runtime.h>
#include <math.h>

#define DIM 384
#define NUM_HEADS 8
#define RES 14
#define RES2 7
#define NPOS 196
#define N2 49
#define DHEAD 64
#define NH_KD 128
#define DH 512
#define OUT_DIM 768
#define BATCH 512
#define SCALE_Q 0.25f

typedef unsigned short u16;
typedef short s16x8 __attribute__((ext_vector_type(8)));
typedef short s16x4 __attribute__((ext_vector_type(4)));
typedef float f32x4 __attribute__((ext_vector_type(4)));
typedef unsigned int u32x2 __attribute__((ext_vector_type(2)));

__device__ __forceinline__ float bf2f(u16 u) {
  union { unsigned int i; float f; } v; v.i = ((unsigned int)u) << 16; return v.f;
}
__device__ __forceinline__ u16 f2bf(float f) {
  union { unsigned int i; float f; } v; v.f = f;
  unsigned int r = v.i + 0x7fffu + ((v.i >> 16) & 1u);
  return (u16)(r >> 16);
}

#define GLD16(gp, lp) __builtin_amdgcn_global_load_lds( \
    (const __attribute__((address_space(1))) void*)(gp), \
    (__attribute__((address_space(3))) void*)(lp), 16, 0, 0)

// ---------- fused prep: weight casts + bias gather in one launch ----------
__global__ __launch_bounds__(256) void k_prep(const float* __restrict__ kw, const float* __restrict__ vw,
                                              const float* __restrict__ qw, const float* __restrict__ pw,
                                              const float* __restrict__ ab, const int* __restrict__ idxs, int noff,
                                              u16* __restrict__ kwb, u16* __restrict__ vwb,
                                              u16* __restrict__ qwb, u16* __restrict__ pwb,
                                              float* __restrict__ bxp) {
  int i = blockIdx.x * 256 + threadIdx.x;
  const int e1 = NH_KD * DIM;                // 49152
  const int e2 = e1 + DH * DIM;              // 245760
  const int e3 = e2 + NH_KD * DIM;           // 294912
  const int e4 = e3 + OUT_DIM * DH;          // 688128
  const int e5 = e4 + NUM_HEADS * N2 * 256;  // 788480
  if (i < e1) kwb[i] = f2bf(kw[i]);
  else if (i < e2) vwb[i - e1] = f2bf(vw[i - e1]);
  else if (i < e3) qwb[i - e2] = f2bf(qw[i - e2]);
  else if (i < e4) pwb[i - e3] = f2bf(pw[i - e3]);
  else if (i < e5) {
    int j = i - e4;
    int f = j & 15, c = (j >> 4) & 15;
    int m = (j >> 8) % N2, h = j / (N2 * 256);
    int n = f * 16 + c;
    bxp[j] = (n < NPOS) ? ab[h * noff + idxs[m * NPOS + n]] : 0.f;
  }
}

// ---------- fused transpose + depthwise dwconv_q, transposed-tile layout ----------
// tileT[196 pos][70 ch-stride] u16 (r13-verified for phases 2/3).
// r14: phase 1 rebuilt for MLP — 12.25 independent f32x4 loads/thread (x rows are
// 49 aligned 16B chunks), consecutive lanes = consecutive 16B (coalesced). Phase 2
// writes xbT as 16B stores (8 ch/thread). Math bit-identical to r13.
__global__ __launch_bounds__(256) void k_transpose_dwq(const float* __restrict__ x, u16* __restrict__ xt,
                                                       const float* __restrict__ qlw, const float* __restrict__ qlb,
                                                       u16* __restrict__ qlt) {
  int b = blockIdx.y, c0 = blockIdx.x * 64;
  __shared__ __align__(8) u16 tileT[196 * 70];   // 27,440 B
  __shared__ float wlds2[576];                   // [tap][64 ch]
  __shared__ float blds[64];
  int tid = threadIdx.x;
  const float* xb = x + (size_t)b * DIM * NPOS;

  // phase 1: 64 ch x 49 f32x4 chunks; all loads independent
  for (int idx = tid; idx < 64 * 49; idx += 256) {
    int ch = idx / 49, p4 = idx - ch * 49;
    f32x4 v = *(const f32x4*)(xb + (size_t)(c0 + ch) * NPOS + p4 * 4);
#pragma unroll
    for (int j = 0; j < 4; j++)
      tileT[(p4 * 4 + j) * 70 + ch] = f2bf(v[j]);
  }
  for (int i = tid; i < 576; i += 256) {
    int c = i / 9, t = i % 9;
    wlds2[t * 64 + c] = qlw[(size_t)(c0 + c) * 9 + t];
  }
  if (tid < 64) blds[tid] = qlb[c0 + tid];
  __syncthreads();

  // phase 2: xbT write, 8 channels per lane, 16B vector stores
  u16* xtb = xt + (size_t)b * NPOS * DIM + c0;
  for (int idx = tid; idx < NPOS * 8; idx += 256) {
    int n = idx >> 3, g = (idx & 7) << 3;
    s16x8 val;
    ((uint*)&val)[0] = *(const uint*)&tileT[n * 70 + g];
    ((uint*)&val)[1] = *(const uint*)&tileT[n * 70 + g + 2];
    ((uint*)&val)[2] = *(const uint*)&tileT[n * 70 + g + 4];
    ((uint*)&val)[3] = *(const uint*)&tileT[n * 70 + g + 6];
    *(s16x8*)(xtb + (size_t)n * DIM + g) = val;
  }
  // phase 3: dwconv, 2 channels per lane, packed 4B stores
  u16* qb = qlt + (size_t)b * N2 * DIM + c0;
  for (int idx = tid; idx < N2 * 32; idx += 256) {
    int cp = idx & 31, n2 = idx >> 5;
    int c = cp << 1;
    int r = n2 / RES2, s = n2 % RES2;
    uint rv = *(const uint*)&tileT[((2 * r) * RES + 2 * s) * 70 + c];
    float a0 = blds[c]     + bf2f((u16)(rv & 0xffff));
    float a1 = blds[c + 1] + bf2f((u16)(rv >> 16));
#pragma unroll
    for (int dy = 0; dy < 3; dy++) {
      int ry = 2 * r - 1 + dy;
      if (ry < 0 || ry >= RES) continue;
#pragma unroll
      for (int dx = 0; dx < 3; dx++) {
        int sx = 2 * s - 1 + dx;
        if (sx < 0 || sx >= RES) continue;
        uint tv = *(const uint*)&tileT[(ry * RES + sx) * 70 + c];
        int t = dy * 3 + dx;
        a0 += wlds2[t * 64 + c]     * bf2f((u16)(tv & 0xffff));
        a1 += wlds2[t * 64 + c + 1] * bf2f((u16)(tv >> 16));
      }
    }
    uint outp = (uint)f2bf(a0) | ((uint)f2bf(a1) << 16);
    *(uint*)(qb + (size_t)n2 * DIM + c) = outp;
  }
}

// ---------- flattened GEMM: C = A[M][K] x B[N][K]^T, both K-contiguous bf16 ----------
// 128x128 tile, BK=64 (two 8KB 32-K halves/operand, one barrier per 64-K), GLD16 staging.
// chunk = 1KB = 16 rows x 64B; wave w stages chunks w*2, w*2+1.
// Source pre-swizzle (m173/rule21): lane fetches global granule (l&3)^((l>>3)&3);
// frag reads un-swizzle with rg8 = ((l>>4)^((l>>1)&3))*8 -> conflict-free both sides.
// SPLN=0: out[m*ldc + n] (ch=n). SPLN>0: out[(n/SPLN)*bstride + m*SPLN + n%SPLN] (ch=m).
// NOTE (r10/r11 lesson): do NOT merge these GEMMs — shared-input segments with different
// tile->XCD locality thrash L2 (gemm3: 117 -> 185 us, FETCH 2x). Keep separate launches.
template <int SPLN, bool F32OUT>
__global__ __launch_bounds__(256) void k_gemm_flat(
    const u16* __restrict__ A, const u16* __restrict__ B, void* __restrict__ C,
    const float* __restrict__ cb, const float* __restrict__ bns, const float* __restrict__ bnt,
    int K, int NMT, int ldc, long bstride) {
  __shared__ __align__(16) u16 a_lds[2 * 128 * 32];
  __shared__ __align__(16) u16 b_lds[2 * 128 * 32];
  int nwg = gridDim.x, bx = blockIdx.x;
  int wg = ((nwg & 7) == 0) ? ((bx & 7) * (nwg >> 3) + (bx >> 3)) : bx;  // XCD-bijective
  int mt = wg % NMT, nt = wg / NMT;                                      // m fastest: j-tile shared on-XCD
  int m0 = mt * 128, n0 = nt * 128;
  int tid = threadIdx.x, w = tid >> 6, l = tid & 63;

  int srow = l >> 2;
  int scol = ((l & 3) ^ ((l >> 3) & 3)) * 8;   // pre-swizzled source granule
  const u16* asrc[2]; const u16* bsrc[2];
#pragma unroll
  for (int c = 0; c < 2; c++) {
    int chunk = w * 2 + c;
    asrc[c] = A + (size_t)(m0 + chunk * 16 + srow) * K + scol;
    bsrc[c] = B + (size_t)(n0 + chunk * 16 + srow) * K + scol;
  }
  char* adst = (char*)a_lds + (w * 2) * 1024 + l * 16;
  char* bdst = (char*)b_lds + (w * 2) * 1024 + l * 16;

  f32x4 acc[4][4];
#pragma unroll
  for (int i = 0; i < 4; i++)
#pragma unroll
    for (int j = 0; j < 4; j++) acc[i][j] = (f32x4){0.f, 0.f, 0.f, 0.f};

  int wm = w >> 1, wn = w & 1;
  int rg8 = ((l >> 4) ^ ((l >> 1) & 3)) * 8;   // un-swizzling read granule
  int arow = wm * 64 + (l & 15);
  int brow = wn * 64 + (l & 15);

  for (int kk = 0; kk < K; kk += 64) {
#pragma unroll
    for (int c = 0; c < 2; c++) {
      GLD16(asrc[c] + kk,      adst + c * 1024);
      GLD16(asrc[c] + kk + 32, adst + 8192 + c * 1024);
      GLD16(bsrc[c] + kk,      bdst + c * 1024);
      GLD16(bsrc[c] + kk + 32, bdst + 8192 + c * 1024);
    }
    __syncthreads();                 // compiler drains vmcnt before barrier
#pragma unroll
    for (int hf = 0; hf < 2; hf++) {
      const u16* ah = a_lds + hf * (128 * 32);
      const u16* bh = b_lds + hf * (128 * 32);
      s16x8 af[4], bf[4];
#pragma unroll
      for (int i = 0; i < 4; i++) {
        af[i] = *(const s16x8*)(&ah[(arow + i * 16) * 32 + rg8]);
        bf[i] = *(const s16x8*)(&bh[(brow + i * 16) * 32 + rg8]);
      }
#pragma unroll
      for (int i = 0; i < 4; i++)
#pragma unroll
        for (int j = 0; j < 4; j++)
          acc[i][j] = __builtin_amdgcn_mfma_f32_16x16x32_bf16(af[i], bf[j], acc[i][j], 0, 0, 0);
    }
    __syncthreads();
  }

  int ncol = l & 15, mq = (l >> 4) * 4;
#pragma unroll
  for (int i = 0; i < 4; i++) {
#pragma unroll
    for (int j = 0; j < 4; j++) {
      int n = n0 + wn * 64 + j * 16 + ncol;
#pragma unroll
      for (int r = 0; r < 4; r++) {
        int m = m0 + wm * 64 + i * 16 + mq + r;
        int ch = SPLN ? m : n;
        float val = acc[i][j][r] * bns[ch] + (cb[ch] * bns[ch] + bnt[ch]);
        size_t o;
        if (SPLN) o = (size_t)(n / SPLN) * bstride + (size_t)m * SPLN + (n % SPLN);
        else      o = (size_t)m * ldc + n;
        if (F32OUT) ((float*)C)[o] = val;
        else        ((u16*)C)[o] = f2bf(val);
      }
    }
  }
}

// ---------- v_local = BN(dwconv_s2(v4) + b) -> vlT (bf16 [b][49][512]) ----------
__global__ __launch_bounds__(256) void k_dwconv_v(const u16* __restrict__ v4, const float* __restrict__ w,
    const float* __restrict__ bias, const float* __restrict__ bns, const float* __restrict__ bnt,
    u16* __restrict__ vlt) {
  int b = blockIdx.y, ct = blockIdx.x;
  __shared__ u16 tile[64][196];
  int tid = threadIdx.x, wave = tid >> 6, lane = tid & 63;
  const u16* vbp = v4 + ((size_t)b * DH + ct * 64) * NPOS;
  for (int r = wave; r < 64; r += 4) {
    const u16* row = vbp + (size_t)r * NPOS;
    tile[r][lane]       = row[lane];
    tile[r][lane + 64]  = row[lane + 64];
    tile[r][lane + 128] = row[lane + 128];
    if (lane < 4) tile[r][lane + 192] = row[lane + 192];
  }
  __syncthreads();
  for (int idx = tid; idx < 64 * N2; idx += 256) {
    int cl = idx & 63, n2 = idx >> 6;
    int ch = ct * 64 + cl;
    int r = n2 / RES2, s = n2 % RES2;
    float acc = bias[ch];
#pragma unroll
    for (int dy = 0; dy < 3; dy++) {
      int ry = 2 * r - 1 + dy;
      if (ry < 0 || ry >= RES) continue;
#pragma unroll
      for (int dx = 0; dx < 3; dx++) {
        int sx = 2 * s - 1 + dx;
        if (sx < 0 || sx >= RES) continue;
        acc += w[ch * 9 + dy * 3 + dx] * bf2f(tile[cl][ry * RES + sx]);
      }
    }
    vlt[((size_t)b * N2 + n2) * DH + ch] = f2bf(acc * bns[ch] + bnt[ch]);
  }
}

// ---------- MFMA attention per (b,h), LDS = p_lds only (29.7 KB) ----------
// Q/K fragments direct from global (part>=2 lanes zero = K 16->32 pad; OOB rows masked).
// V direct from v4 ([b][512][196] = B-operand rows) as 2x8B. o_lds overlaps p_lds.
__global__ __launch_bounds__(256, 4) void k_attn_mfma(const u16* __restrict__ qT, const u16* __restrict__ kT,
    const u16* __restrict__ v4, const float* __restrict__ bxp, const u16* __restrict__ vlT,
    u16* __restrict__ gT) {
  int h = blockIdx.x, b = blockIdx.y;
  __shared__ __align__(16) u16 p_lds[64 * 232];   // 29,696 B
  float* o_lds = (float*)p_lds;                   // overlap (barrier-protected)
  int tid = threadIdx.x, w = tid >> 6, l = tid & 63;
  int part = l >> 4, row16 = l & 15;
  int mbase = w * 16 + part * 4;
  int ncol = l & 15;

  for (int idx = tid; idx < 64 * 8; idx += 256)
    ((uint*)&p_lds[(idx >> 3) * 232])[104 + (idx & 7)] = 0;

  s16x8 af = (s16x8){0, 0, 0, 0, 0, 0, 0, 0};
  if (part < 2)
    af = *(const s16x8*)(qT + ((size_t)b * N2 + (w * 16 + row16)) * NH_KD + h * 16 + part * 8);

  const u16* kbase = kT + (size_t)b * NPOS * NH_KD + h * 16 + part * 8;
  f32x4 s[13];
#pragma unroll
  for (int f = 0; f < 13; f++) {
    s16x8 bf = (s16x8){0, 0, 0, 0, 0, 0, 0, 0};
    if (part < 2)
      bf = *(const s16x8*)(kbase + (size_t)(f * 16 + row16) * NH_KD);
    s[f] = __builtin_amdgcn_mfma_f32_16x16x32_bf16(af, bf, (f32x4){0.f, 0.f, 0.f, 0.f}, 0, 0, 0);
  }

  const u16* vbase = v4 + ((size_t)b * DH + h * DHEAD) * NPOS;
  int vd = l & 15, vq8 = part * 8;
  auto VLOAD = [&](int f, int kk) {
    const u16* p = vbase + (size_t)(f * 16 + vd) * NPOS + kk + vq8;
    s16x8 r;
    ((u32x2*)&r)[0] = *(const u32x2*)(p);
    ((u32x2*)&r)[1] = *(const u32x2*)(p + 4);
    return r;
  };
  s16x8 vb0[4];
#pragma unroll
  for (int f = 0; f < 4; f++) vb0[f] = VLOAD(f, 0);

#pragma unroll
  for (int q = 0; q < 4; q++) {
    f32x4 bqr[4];
#pragma unroll
    for (int r = 0; r < 4; r++) {
      int mm = mbase + r; if (mm > N2 - 1) mm = N2 - 1;
      bqr[r] = *(const f32x4*)(bxp + (((size_t)h * N2 + mm) * 16 + ncol) * 16 + q * 4);
    }
#pragma unroll
    for (int ff = 0; ff < 4; ff++) {
      int f = q * 4 + ff;
      if (f < 13) {
        int n = f * 16 + ncol;
#pragma unroll
        for (int r = 0; r < 4; r++) {
          int m = mbase + r;
          s[f][r] = (m < N2 && n < NPOS) ? s[f][r] * SCALE_Q + bqr[r][ff] : -1e30f;
        }
      }
    }
  }
#pragma unroll
  for (int r = 0; r < 4; r++) {
    float mx = s[0][r];
#pragma unroll
    for (int f = 1; f < 13; f++) mx = fmaxf(mx, s[f][r]);
    mx = fmaxf(mx, __shfl_xor(mx, 1)); mx = fmaxf(mx, __shfl_xor(mx, 2));
    mx = fmaxf(mx, __shfl_xor(mx, 4)); mx = fmaxf(mx, __shfl_xor(mx, 8));
    float sum = 0.f;
#pragma unroll
    for (int f = 0; f < 13; f++) { s[f][r] = __expf(s[f][r] - mx); sum += s[f][r]; }
    sum += __shfl_xor(sum, 1); sum += __shfl_xor(sum, 2);
    sum += __shfl_xor(sum, 4); sum += __shfl_xor(sum, 8);
    float inv = 1.f / sum;
#pragma unroll
    for (int f = 0; f < 13; f++) s[f][r] *= inv;
  }
#pragma unroll
  for (int f = 0; f < 13; f++) {
    int n = f * 16 + ncol;
#pragma unroll
    for (int r = 0; r < 4; r++)
      p_lds[(mbase + r) * 232 + n] = f2bf(s[f][r]);
  }
  __syncthreads();

  f32x4 o[4];
#pragma unroll
  for (int f = 0; f < 4; f++) o[f] = (f32x4){0.f, 0.f, 0.f, 0.f};
#pragma unroll
  for (int t = 0; t < 7; t++) {
    int kk = t * 32;
    s16x8 vn[4];
    if (t < 6) {
#pragma unroll
      for (int f = 0; f < 4; f++) vn[f] = VLOAD(f, kk + 32);
    }
    s16x8 pa = *(const s16x8*)(&p_lds[(w * 16 + row16) * 232 + kk + part * 8]);
#pragma unroll
    for (int f = 0; f < 4; f++)
      o[f] = __builtin_amdgcn_mfma_f32_16x16x32_bf16(pa, vb0[f], o[f], 0, 0, 0);
    if (t < 6) {
#pragma unroll
      for (int f = 0; f < 4; f++) vb0[f] = vn[f];
    }
  }
  __syncthreads();

#pragma unroll
  for (int f = 0; f < 4; f++)
#pragma unroll
    for (int r = 0; r < 4; r++) {
      int m = mbase + r;
      if (m < N2) o_lds[m * 68 + f * 16 + ncol] = o[f][r];
    }
  __syncthreads();

  for (int idx = tid; idx < N2 * 16; idx += 256) {
    int row = idx >> 4, c4 = (idx & 15) << 2;
    f32x4 ov = *(const f32x4*)(&o_lds[row * 68 + c4]);
    size_t go = ((size_t)b * N2 + row) * DH + h * DHEAD + c4;
    s16x4 vv = *(const s16x4*)(vlT + go);
    s16x4 outv;
#pragma unroll
    for (int e = 0; e < 4; e++) {
      float xv = ov[e] + bf2f((u16)vv[e]);
      float g = 0.5f * xv * (1.f + erff(xv * 0.70710678118f));
      outv[e] = (short)f2bf(g);
    }
    *(s16x4*)(gT + go) = outv;
  }
}

extern "C" void kernel_launch(void* const* d_in, const int* in_sizes, int n_in,
                              void* d_out, int out_size, void* d_ws, size_t ws_size,
                              hipStream_t stream) {
  const float* x   = (const float*)d_in[0];
  const float* qlw = (const float*)d_in[1];
  const float* qlb = (const float*)d_in[2];
  const float* qpw = (const float*)d_in[3];
  const float* qpb = (const float*)d_in[4];
  const float* qbs = (const float*)d_in[5];
  const float* qbt = (const float*)d_in[6];
  const float* kw  = (const float*)d_in[7];
  const float* kb  = (const float*)d_in[8];
  const float* kbs = (const float*)d_in[9];
  const float* kbt = (const float*)d_in[10];
  const float* vw  = (const float*)d_in[11];
  const float* vb  = (const float*)d_in[12];
  const float* vbs = (const float*)d_in[13];
  const float* vbt = (const float*)d_in[14];
  const float* vlw = (const float*)d_in[15];
  const float* vlb = (const float*)d_in[16];
  const float* vls = (const float*)d_in[17];
  const float* vlt_in = (const float*)d_in[18];
  const float* pw  = (const float*)d_in[19];
  const float* pb  = (const float*)d_in[20];
  const float* pbs = (const float*)d_in[21];
  const float* pbt = (const float*)d_in[22];
  const float* ab  = (const float*)d_in[23];
  const int*   bidx = (const int*)d_in[24];
  int noff = in_sizes[23] / NUM_HEADS;

  char* ws = (char*)d_ws;
  size_t off = 0;
  auto alloc = [&](size_t bytes) { char* p = ws + off; off += (bytes + 255) & ~(size_t)255; return p; };
  u16* xbT = (u16*)alloc((size_t)BATCH * NPOS * DIM * 2);      // 77.1 MB (aliased by gT later)
  u16* kTm = (u16*)alloc((size_t)BATCH * NPOS * NH_KD * 2);    // 25.7 MB
  u16* qlT = (u16*)alloc((size_t)BATCH * N2 * DIM * 2);        // 19.3 MB
  u16* qTm = (u16*)alloc((size_t)BATCH * N2 * NH_KD * 2);      //  6.4 MB
  u16* v4m = (u16*)alloc((size_t)BATCH * DH * NPOS * 2);       // 102.8 MB
  u16* vlTm = (u16*)alloc((size_t)BATCH * N2 * DH * 2);        // 25.7 MB  (absorbs attn's OOB V reads)
  float* bxp = (float*)alloc((size_t)NUM_HEADS * N2 * 16 * 16 * 4);  // 0.8 MB
  u16* kwb = (u16*)alloc((size_t)NH_KD * DIM * 2);
  u16* vwb = (u16*)alloc((size_t)DH * DIM * 2);
  u16* qwb = (u16*)alloc((size_t)NH_KD * DIM * 2);
  u16* pwb = (u16*)alloc((size_t)OUT_DIM * DH * 2);
  u16* gTm = xbT;  // alias: all xbT readers complete before k_attn writes gT

  k_prep<<<(788480 + 255) / 256, 256, 0, stream>>>(kw, vw, qpw, pw, ab, bidx, noff,
                                                   kwb, vwb, qwb, pwb, bxp);

  // transpose + fused depthwise q-conv (transposed-tile layout, MLP phase 1)
  k_transpose_dwq<<<dim3(6, BATCH), 256, 0, stream>>>(x, xbT, qlw, qlb, qlT);

  // k: A=xbT[100352][384] (m=j), B=kwb[128][384] (n=ch) -> kTm[j][128]; 784 m-tiles x 1 n-tile
  k_gemm_flat<0, false><<<784, 256, 0, stream>>>(
      xbT, kwb, kTm, kb, kbs, kbt, DIM, 784, NH_KD, 0);
  // v: A=vwb[512][384] (m=ch), B=xbT (n=j) -> v4m[b][512][196]; 4 m-tiles x 784 n-tiles
  k_gemm_flat<NPOS, false><<<3136, 256, 0, stream>>>(
      vwb, xbT, v4m, vb, vbs, vbt, DIM, 4, 0, (long)DH * NPOS);
  // q: A=qlT[25088][384] (m=j), B=qwb (n=ch) -> qTm[j][128]; 196 m-tiles x 1 n-tile
  k_gemm_flat<0, false><<<196, 256, 0, stream>>>(
      qlT, qwb, qTm, qpb, qbs, qbt, DIM, 196, NH_KD, 0);

  k_dwconv_v<<<dim3(8, BATCH), 256, 0, stream>>>(v4m, vlw, vlb, vls, vlt_in, vlTm);
  k_attn_mfma<<<dim3(NUM_HEADS, BATCH), 256, 0, stream>>>(qTm, kTm, v4m, bxp, vlTm, gTm);

  // p: A=pwb[768][512] (m=ch), B=gTm[25088][512] (n=j) -> d_out[b][768][49] f32; 6 x 196
  k_gemm_flat<N2, true><<<1176, 256, 0, stream>>>(
      pwb, gTm, d_out, pb, pbs, pbt, DH, 6, 0, (long)OUT_DIM * N2);
}